// Round 1
// baseline (601.413 us; speedup 1.0000x reference)
//
#include <hip/hip_runtime.h>
#include <cstdint>
#include <cstddef>

typedef __attribute__((ext_vector_type(8))) short bf16x8;
typedef __attribute__((ext_vector_type(4))) float f32x4;

#define B_ 4
#define T_ 2048
#define DM 1024
#define NH 16
#define HD 64

static __device__ __forceinline__ unsigned short f2bf(float f) {
  union { float f; unsigned int u; } v; v.f = f;
  unsigned int r = v.u + 0x7FFFu + ((v.u >> 16) & 1u);
  return (unsigned short)(r >> 16);
}
static __device__ __forceinline__ float b2f(unsigned short u) {
  union { unsigned int u; float f; } v; v.u = ((unsigned int)u) << 16;
  return v.f;
}

// ---------------- cast f32 -> bf16 (vectorized) ----------------
__global__ void cast_f32_to_bf16(const float* __restrict__ in,
                                 unsigned short* __restrict__ out, int n8) {
  for (int i = blockIdx.x * blockDim.x + threadIdx.x; i < n8;
       i += gridDim.x * blockDim.x) {
    const float4* p = (const float4*)(in + (size_t)i * 8);
    float4 a = p[0], b = p[1];
    bf16x8 o;
    o[0] = f2bf(a.x); o[1] = f2bf(a.y); o[2] = f2bf(a.z); o[3] = f2bf(a.w);
    o[4] = f2bf(b.x); o[5] = f2bf(b.y); o[6] = f2bf(b.z); o[7] = f2bf(b.w);
    *(bf16x8*)(out + (size_t)i * 8) = o;
  }
}

// ---------------- transpose + cast: in f32 [R][C] -> out bf16 [C][R] --------
__global__ void transpose_cast(const float* __restrict__ in,
                               unsigned short* __restrict__ out, int R, int C) {
  __shared__ unsigned short tile[32][33];
  int c0 = blockIdx.x * 32, r0 = blockIdx.y * 32;
  int tx = threadIdx.x, ty = threadIdx.y;
#pragma unroll
  for (int j = 0; j < 32; j += 8) {
    float v = in[(size_t)(r0 + ty + j) * C + c0 + tx];
    tile[tx][ty + j] = f2bf(v);
  }
  __syncthreads();
#pragma unroll
  for (int j = 0; j < 32; j += 8) {
    out[(size_t)(c0 + ty + j) * R + r0 + tx] = tile[ty + j][tx];
  }
}

// ---------------- GEMM (A [M][1024] bf16, Bt [N][1024] bf16) ----------------
#define BM 128
#define BN 128
#define BKg 64
#define LDK 72  // padded row (elems), keeps 16B alignment, ~2-way banks

// QKV GEMM: scatters output to Q [bh][t][64], K [bh][t][64], VT [bh][64][t]
__global__ __launch_bounds__(256) void gemm_qkv(
    const unsigned short* __restrict__ A, const unsigned short* __restrict__ Bt,
    unsigned short* __restrict__ Qo, unsigned short* __restrict__ Ko,
    unsigned short* __restrict__ VTo) {
  __shared__ __align__(16) unsigned short As[BM * LDK];
  __shared__ __align__(16) unsigned short Bs[BN * LDK];
  const int Kd = 1024;
  int m0 = blockIdx.y * BM;
  int n0 = blockIdx.x * BN;
  int t = threadIdx.x;
  int w = t >> 6, l = t & 63;
  int wr = w >> 1, wc = w & 1;
  int lr = l & 15, lg = l >> 4;
  f32x4 acc[4][4];
#pragma unroll
  for (int i = 0; i < 4; i++)
#pragma unroll
    for (int j = 0; j < 4; j++) acc[i][j] = (f32x4)0.f;

  for (int k0 = 0; k0 < Kd; k0 += BKg) {
#pragma unroll
    for (int i = 0; i < 4; i++) {
      int c = t + i * 256;
      int row = c >> 3, ch = c & 7;
      *(bf16x8*)(&As[row * LDK + ch * 8]) =
          *(const bf16x8*)(A + (size_t)(m0 + row) * Kd + k0 + ch * 8);
      *(bf16x8*)(&Bs[row * LDK + ch * 8]) =
          *(const bf16x8*)(Bt + (size_t)(n0 + row) * Kd + k0 + ch * 8);
    }
    __syncthreads();
#pragma unroll
    for (int kk = 0; kk < 2; kk++) {
      bf16x8 af[4], bfr[4];
#pragma unroll
      for (int mi = 0; mi < 4; mi++)
        af[mi] = *(const bf16x8*)(&As[(wr * 64 + mi * 16 + lr) * LDK + kk * 32 + lg * 8]);
#pragma unroll
      for (int ni = 0; ni < 4; ni++)
        bfr[ni] = *(const bf16x8*)(&Bs[(wc * 64 + ni * 16 + lr) * LDK + kk * 32 + lg * 8]);
#pragma unroll
      for (int mi = 0; mi < 4; mi++)
#pragma unroll
        for (int ni = 0; ni < 4; ni++)
          acc[mi][ni] = __builtin_amdgcn_mfma_f32_16x16x32_bf16(
              af[mi], bfr[ni], acc[mi][ni], 0, 0, 0);
    }
    __syncthreads();
  }
#pragma unroll
  for (int mi = 0; mi < 4; mi++) {
#pragma unroll
    for (int ni = 0; ni < 4; ni++) {
      int col = n0 + wc * 64 + ni * 16 + lr;
      int which = col >> 10, hd = col & 1023;
      int h = hd >> 6, d = hd & 63;
#pragma unroll
      for (int r = 0; r < 4; r++) {
        int row = m0 + wr * 64 + mi * 16 + lg * 4 + r;
        int b = row >> 11, tt = row & 2047;
        unsigned short bv = f2bf(acc[mi][ni][r]);
        size_t bh = (size_t)(b * NH + h);
        if (which == 0)
          Qo[(bh * T_ + tt) * HD + d] = bv;
        else if (which == 1)
          Ko[(bh * T_ + tt) * HD + d] = bv;
        else
          VTo[(bh * HD + d) * T_ + tt] = bv;
      }
    }
  }
}

// Proj GEMM: A [8192][1024] bf16 @ Bt [1024][1024] bf16 -> C f32 [8192][1024]
__global__ __launch_bounds__(256) void gemm_proj(
    const unsigned short* __restrict__ A, const unsigned short* __restrict__ Bt,
    float* __restrict__ C) {
  __shared__ __align__(16) unsigned short As[BM * LDK];
  __shared__ __align__(16) unsigned short Bs[BN * LDK];
  const int Kd = 1024;
  int m0 = blockIdx.y * BM;
  int n0 = blockIdx.x * BN;
  int t = threadIdx.x;
  int w = t >> 6, l = t & 63;
  int wr = w >> 1, wc = w & 1;
  int lr = l & 15, lg = l >> 4;
  f32x4 acc[4][4];
#pragma unroll
  for (int i = 0; i < 4; i++)
#pragma unroll
    for (int j = 0; j < 4; j++) acc[i][j] = (f32x4)0.f;

  for (int k0 = 0; k0 < Kd; k0 += BKg) {
#pragma unroll
    for (int i = 0; i < 4; i++) {
      int c = t + i * 256;
      int row = c >> 3, ch = c & 7;
      *(bf16x8*)(&As[row * LDK + ch * 8]) =
          *(const bf16x8*)(A + (size_t)(m0 + row) * Kd + k0 + ch * 8);
      *(bf16x8*)(&Bs[row * LDK + ch * 8]) =
          *(const bf16x8*)(Bt + (size_t)(n0 + row) * Kd + k0 + ch * 8);
    }
    __syncthreads();
#pragma unroll
    for (int kk = 0; kk < 2; kk++) {
      bf16x8 af[4], bfr[4];
#pragma unroll
      for (int mi = 0; mi < 4; mi++)
        af[mi] = *(const bf16x8*)(&As[(wr * 64 + mi * 16 + lr) * LDK + kk * 32 + lg * 8]);
#pragma unroll
      for (int ni = 0; ni < 4; ni++)
        bfr[ni] = *(const bf16x8*)(&Bs[(wc * 64 + ni * 16 + lr) * LDK + kk * 32 + lg * 8]);
#pragma unroll
      for (int mi = 0; mi < 4; mi++)
#pragma unroll
        for (int ni = 0; ni < 4; ni++)
          acc[mi][ni] = __builtin_amdgcn_mfma_f32_16x16x32_bf16(
              af[mi], bfr[ni], acc[mi][ni], 0, 0, 0);
    }
    __syncthreads();
  }
#pragma unroll
  for (int mi = 0; mi < 4; mi++) {
#pragma unroll
    for (int ni = 0; ni < 4; ni++) {
      int col = n0 + wc * 64 + ni * 16 + lr;
#pragma unroll
      for (int r = 0; r < 4; r++) {
        int row = m0 + wr * 64 + mi * 16 + lg * 4 + r;
        C[(size_t)row * 1024 + col] = acc[mi][ni][r];
      }
    }
  }
}

// ---------------- RoPE on Q and K (in place); Q gets 1/sqrt(hd) folded ------
__global__ void rope_kernel(unsigned short* __restrict__ Q,
                            unsigned short* __restrict__ K,
                            const float* __restrict__ cosT,
                            const float* __restrict__ sinT) {
  const int nchunk = B_ * NH * T_ * (HD / 8);  // 1048576
  for (int idx = blockIdx.x * blockDim.x + threadIdx.x; idx < 2 * nchunk;
       idx += gridDim.x * blockDim.x) {
    int which = idx >= nchunk;
    int c = which ? idx - nchunk : idx;
    unsigned short* base = which ? K : Q;
    int ch = c & 7;
    int row = c >> 3;
    int tt = row & (T_ - 1);
    bf16x8 v = *(bf16x8*)(base + (size_t)row * HD + ch * 8);
    float scale = which ? 1.0f : 0.125f;
#pragma unroll
    for (int p = 0; p < 4; p++) {
      int fi = ch * 4 + p;
      float cc = cosT[tt * 32 + fi], ss = sinT[tt * 32 + fi];
      float x1 = b2f((unsigned short)v[2 * p]);
      float x2 = b2f((unsigned short)v[2 * p + 1]);
      v[2 * p] = (short)f2bf((x1 * cc - x2 * ss) * scale);
      v[2 * p + 1] = (short)f2bf((x2 * cc + x1 * ss) * scale);
    }
    *(bf16x8*)(base + (size_t)row * HD + ch * 8) = v;
  }
}

// ---------------- Flash attention (causal), 4 waves, 64 q-rows/block --------
__global__ __launch_bounds__(256) void attn_kernel(
    const unsigned short* __restrict__ Q, const unsigned short* __restrict__ K,
    const unsigned short* __restrict__ VT, unsigned short* __restrict__ O) {
  __shared__ __align__(16) unsigned short P_lds[4][16 * 72];
  int blk = blockIdx.x;
  int bh = blk >> 5;  // T/64 = 32 q-tiles per (b,h)
  int qt = blk & 31;
  int b = bh >> 4, h = bh & 15;
  int t = threadIdx.x;
  int w = t >> 6, l = t & 63;
  int lr = l & 15, lg = l >> 4;
  int q0 = qt * 64 + w * 16;  // absolute first q-row of this wave

  const unsigned short* Qb = Q + (size_t)bh * T_ * HD;
  const unsigned short* Kb = K + (size_t)bh * T_ * HD;
  const unsigned short* Vb = VT + (size_t)bh * HD * T_;

  bf16x8 aq[2];
#pragma unroll
  for (int kd = 0; kd < 2; kd++)
    aq[kd] = *(const bf16x8*)(Qb + (size_t)(q0 + lr) * HD + kd * 32 + lg * 8);

  f32x4 o[4];
#pragma unroll
  for (int f = 0; f < 4; f++) o[f] = (f32x4)0.f;
  float mrow[4] = {-1e30f, -1e30f, -1e30f, -1e30f};
  float lrow[4] = {0.f, 0.f, 0.f, 0.f};

  for (int j = 0; j <= qt; j++) {
    int t0 = j * 64;
    f32x4 s[4];
#pragma unroll
    for (int sf = 0; sf < 4; sf++) {
      s[sf] = (f32x4)0.f;
#pragma unroll
      for (int kd = 0; kd < 2; kd++) {
        bf16x8 bk = *(const bf16x8*)(Kb + (size_t)(t0 + sf * 16 + lr) * HD +
                                     kd * 32 + lg * 8);
        s[sf] = __builtin_amdgcn_mfma_f32_16x16x32_bf16(aq[kd], bk, s[sf], 0, 0, 0);
      }
    }
    if (j == qt) {  // diagonal tile: causal mask
#pragma unroll
      for (int sf = 0; sf < 4; sf++) {
        int tcol = t0 + sf * 16 + lr;
#pragma unroll
        for (int r = 0; r < 4; r++) {
          int qrow = q0 + lg * 4 + r;
          if (tcol > qrow) s[sf][r] = -1e30f;
        }
      }
    }
    // online softmax (row stats live per-lane for rows lg*4+r)
    float alpha[4];
#pragma unroll
    for (int r = 0; r < 4; r++) {
      float v = fmaxf(fmaxf(s[0][r], s[1][r]), fmaxf(s[2][r], s[3][r]));
#pragma unroll
      for (int off = 1; off < 16; off <<= 1) v = fmaxf(v, __shfl_xor(v, off, 64));
      float mnew = fmaxf(mrow[r], v);
      alpha[r] = __expf(mrow[r] - mnew);
      mrow[r] = mnew;
    }
    float rsum[4] = {0.f, 0.f, 0.f, 0.f};
#pragma unroll
    for (int sf = 0; sf < 4; sf++) {
#pragma unroll
      for (int r = 0; r < 4; r++) {
        float p = __expf(s[sf][r] - mrow[r]);
        s[sf][r] = p;
        rsum[r] += p;
      }
    }
#pragma unroll
    for (int r = 0; r < 4; r++) {
#pragma unroll
      for (int off = 1; off < 16; off <<= 1) rsum[r] += __shfl_xor(rsum[r], off, 64);
      lrow[r] = lrow[r] * alpha[r] + rsum[r];
    }
#pragma unroll
    for (int f = 0; f < 4; f++)
#pragma unroll
      for (int r = 0; r < 4; r++) o[f][r] *= alpha[r];
    // P -> bf16 -> per-wave LDS (C-layout -> A-operand layout transpose)
#pragma unroll
    for (int sf = 0; sf < 4; sf++)
#pragma unroll
      for (int r = 0; r < 4; r++)
        P_lds[w][(lg * 4 + r) * 72 + sf * 16 + lr] = f2bf(s[sf][r]);
    // PV
#pragma unroll
    for (int kd2 = 0; kd2 < 2; kd2++) {
      bf16x8 ap = *(const bf16x8*)(&P_lds[w][lr * 72 + kd2 * 32 + lg * 8]);
#pragma unroll
      for (int f = 0; f < 4; f++) {
        bf16x8 bv = *(const bf16x8*)(Vb + (size_t)(f * 16 + lr) * T_ + t0 +
                                     kd2 * 32 + lg * 8);
        o[f] = __builtin_amdgcn_mfma_f32_16x16x32_bf16(ap, bv, o[f], 0, 0, 0);
      }
    }
  }
  // epilogue: O[b][t][h*64+d] bf16
#pragma unroll
  for (int f = 0; f < 4; f++) {
    int d = f * 16 + lr;
#pragma unroll
    for (int r = 0; r < 4; r++) {
      int qrow = q0 + lg * 4 + r;
      float val = o[f][r] / lrow[r];
      O[((size_t)b * T_ + qrow) * DM + h * HD + d] = f2bf(val);
    }
  }
}

extern "C" void kernel_launch(void* const* d_in, const int* in_sizes, int n_in,
                              void* d_out, int out_size, void* d_ws,
                              size_t ws_size, hipStream_t stream) {
  const float* x = (const float*)d_in[0];
  const float* cosT = (const float*)d_in[1];
  const float* sinT = (const float*)d_in[2];
  const float* w_qkv = (const float*)d_in[3];
  const float* w_proj = (const float*)d_in[4];
  float* out = (float*)d_out;

  char* ws = (char*)d_ws;
  unsigned short* x16 = (unsigned short*)(ws);               // 16 MB
  unsigned short* wqkvT = (unsigned short*)(ws + (16 << 20));   // 6 MB
  unsigned short* wprojT = (unsigned short*)(ws + (22 << 20));  // 2 MB
  unsigned short* Qb = (unsigned short*)(ws + (24 << 20));      // 16 MB
  unsigned short* Kb = (unsigned short*)(ws + (40 << 20));      // 16 MB
  unsigned short* VTb = (unsigned short*)(ws + (56 << 20));     // 16 MB
  unsigned short* Ob = x16;  // reuse: x16 dead after gemm_qkv

  cast_f32_to_bf16<<<2048, 256, 0, stream>>>(x, x16, (B_ * T_ * DM) / 8);
  transpose_cast<<<dim3(3072 / 32, 1024 / 32), dim3(32, 8), 0, stream>>>(
      w_qkv, wqkvT, 1024, 3072);
  transpose_cast<<<dim3(1024 / 32, 1024 / 32), dim3(32, 8), 0, stream>>>(
      w_proj, wprojT, 1024, 1024);
  gemm_qkv<<<dim3(3072 / BN, (B_ * T_) / BM), 256, 0, stream>>>(x16, wqkvT, Qb,
                                                                Kb, VTb);
  rope_kernel<<<4096, 256, 0, stream>>>(Qb, Kb, cosT, sinT);
  attn_kernel<<<dim3(B_ * NH * (T_ / 64)), 256, 0, stream>>>(Qb, Kb, VTb, Ob);
  gemm_proj<<<dim3(1024 / BN, (B_ * T_) / BM), 256, 0, stream>>>(Ob, wprojT, out);
}

// Round 3
// 256.934 us; speedup vs baseline: 2.3407x; 2.3407x over previous
//
#include <hip/hip_runtime.h>
#include <cstdint>
#include <cstddef>

typedef __attribute__((ext_vector_type(8))) short bf16x8;
typedef __attribute__((ext_vector_type(4))) float f32x4;

#define B_ 4
#define T_ 2048
#define DM 1024
#define NH 16
#define HD 64

static __device__ __forceinline__ unsigned short f2bf(float f) {
  union { float f; unsigned int u; } v; v.f = f;
  unsigned int r = v.u + 0x7FFFu + ((v.u >> 16) & 1u);
  return (unsigned short)(r >> 16);
}
static __device__ __forceinline__ float b2f(unsigned short u) {
  union { unsigned int u; float f; } v; v.u = ((unsigned int)u) << 16;
  return v.f;
}

static __device__ __forceinline__ void gll16(const void* g, void* l) {
  __builtin_amdgcn_global_load_lds(
      (const __attribute__((address_space(1))) void*)g,
      (__attribute__((address_space(3))) void*)l, 16, 0, 0);
}

#define BARRIER() do { asm volatile("" ::: "memory"); __builtin_amdgcn_s_barrier(); asm volatile("" ::: "memory"); } while (0)
#define WAITV0() asm volatile("s_waitcnt vmcnt(0)" ::: "memory")

// ---------------- cast f32 -> bf16 (vectorized) ----------------
__global__ void cast_f32_to_bf16(const float* __restrict__ in,
                                 unsigned short* __restrict__ out, int n8) {
  for (int i = blockIdx.x * blockDim.x + threadIdx.x; i < n8;
       i += gridDim.x * blockDim.x) {
    const float4* p = (const float4*)(in + (size_t)i * 8);
    float4 a = p[0], b = p[1];
    bf16x8 o;
    o[0] = f2bf(a.x); o[1] = f2bf(a.y); o[2] = f2bf(a.z); o[3] = f2bf(a.w);
    o[4] = f2bf(b.x); o[5] = f2bf(b.y); o[6] = f2bf(b.z); o[7] = f2bf(b.w);
    *(bf16x8*)(out + (size_t)i * 8) = o;
  }
}

// ---------------- transpose + cast: in f32 [R][C] -> out bf16 [C][R] --------
__global__ void transpose_cast(const float* __restrict__ in,
                               unsigned short* __restrict__ out, int R, int C) {
  __shared__ unsigned short tile[32][33];
  int c0 = blockIdx.x * 32, r0 = blockIdx.y * 32;
  int tx = threadIdx.x, ty = threadIdx.y;
#pragma unroll
  for (int j = 0; j < 32; j += 8) {
    float v = in[(size_t)(r0 + ty + j) * C + c0 + tx];
    tile[tx][ty + j] = f2bf(v);
  }
  __syncthreads();
#pragma unroll
  for (int j = 0; j < 32; j += 8) {
    out[(size_t)(c0 + ty + j) * R + r0 + tx] = tile[ty + j][tx];
  }
}

// ---------------- GEMM (A [M][1024] bf16, Bt [N][1024] bf16) ----------------
#define BM 128
#define BN 128
#define BKg 64
#define LDK 72  // padded row (elems), keeps 16B alignment, ~2-way banks

// QKV GEMM: scatters output to Q [bh][t][64], K [bh][t][64], VT [bh][64][t]
__global__ __launch_bounds__(256) void gemm_qkv(
    const unsigned short* __restrict__ A, const unsigned short* __restrict__ Bt,
    unsigned short* __restrict__ Qo, unsigned short* __restrict__ Ko,
    unsigned short* __restrict__ VTo) {
  __shared__ __align__(16) unsigned short As[BM * LDK];
  __shared__ __align__(16) unsigned short Bs[BN * LDK];
  const int Kd = 1024;
  int m0 = blockIdx.y * BM;
  int n0 = blockIdx.x * BN;
  int t = threadIdx.x;
  int w = t >> 6, l = t & 63;
  int wr = w >> 1, wc = w & 1;
  int lr = l & 15, lg = l >> 4;
  f32x4 acc[4][4];
#pragma unroll
  for (int i = 0; i < 4; i++)
#pragma unroll
    for (int j = 0; j < 4; j++) acc[i][j] = (f32x4)0.f;

  for (int k0 = 0; k0 < Kd; k0 += BKg) {
#pragma unroll
    for (int i = 0; i < 4; i++) {
      int c = t + i * 256;
      int row = c >> 3, ch = c & 7;
      *(bf16x8*)(&As[row * LDK + ch * 8]) =
          *(const bf16x8*)(A + (size_t)(m0 + row) * Kd + k0 + ch * 8);
      *(bf16x8*)(&Bs[row * LDK + ch * 8]) =
          *(const bf16x8*)(Bt + (size_t)(n0 + row) * Kd + k0 + ch * 8);
    }
    __syncthreads();
#pragma unroll
    for (int kk = 0; kk < 2; kk++) {
      bf16x8 af[4], bfr[4];
#pragma unroll
      for (int mi = 0; mi < 4; mi++)
        af[mi] = *(const bf16x8*)(&As[(wr * 64 + mi * 16 + lr) * LDK + kk * 32 + lg * 8]);
#pragma unroll
      for (int ni = 0; ni < 4; ni++)
        bfr[ni] = *(const bf16x8*)(&Bs[(wc * 64 + ni * 16 + lr) * LDK + kk * 32 + lg * 8]);
#pragma unroll
      for (int mi = 0; mi < 4; mi++)
#pragma unroll
        for (int ni = 0; ni < 4; ni++)
          acc[mi][ni] = __builtin_amdgcn_mfma_f32_16x16x32_bf16(
              af[mi], bfr[ni], acc[mi][ni], 0, 0, 0);
    }
    __syncthreads();
  }
#pragma unroll
  for (int mi = 0; mi < 4; mi++) {
#pragma unroll
    for (int ni = 0; ni < 4; ni++) {
      int col = n0 + wc * 64 + ni * 16 + lr;
      int which = col >> 10, hd = col & 1023;
      int h = hd >> 6, d = hd & 63;
#pragma unroll
      for (int r = 0; r < 4; r++) {
        int row = m0 + wr * 64 + mi * 16 + lg * 4 + r;
        int b = row >> 11, tt = row & 2047;
        unsigned short bv = f2bf(acc[mi][ni][r]);
        size_t bh = (size_t)(b * NH + h);
        if (which == 0)
          Qo[(bh * T_ + tt) * HD + d] = bv;
        else if (which == 1)
          Ko[(bh * T_ + tt) * HD + d] = bv;
        else
          VTo[(bh * HD + d) * T_ + tt] = bv;
      }
    }
  }
}

// Proj GEMM: A [8192][1024] bf16 @ Bt [1024][1024] bf16 -> C f32 [8192][1024]
__global__ __launch_bounds__(256) void gemm_proj(
    const unsigned short* __restrict__ A, const unsigned short* __restrict__ Bt,
    float* __restrict__ C) {
  __shared__ __align__(16) unsigned short As[BM * LDK];
  __shared__ __align__(16) unsigned short Bs[BN * LDK];
  const int Kd = 1024;
  int m0 = blockIdx.y * BM;
  int n0 = blockIdx.x * BN;
  int t = threadIdx.x;
  int w = t >> 6, l = t & 63;
  int wr = w >> 1, wc = w & 1;
  int lr = l & 15, lg = l >> 4;
  f32x4 acc[4][4];
#pragma unroll
  for (int i = 0; i < 4; i++)
#pragma unroll
    for (int j = 0; j < 4; j++) acc[i][j] = (f32x4)0.f;

  for (int k0 = 0; k0 < Kd; k0 += BKg) {
#pragma unroll
    for (int i = 0; i < 4; i++) {
      int c = t + i * 256;
      int row = c >> 3, ch = c & 7;
      *(bf16x8*)(&As[row * LDK + ch * 8]) =
          *(const bf16x8*)(A + (size_t)(m0 + row) * Kd + k0 + ch * 8);
      *(bf16x8*)(&Bs[row * LDK + ch * 8]) =
          *(const bf16x8*)(Bt + (size_t)(n0 + row) * Kd + k0 + ch * 8);
    }
    __syncthreads();
#pragma unroll
    for (int kk = 0; kk < 2; kk++) {
      bf16x8 af[4], bfr[4];
#pragma unroll
      for (int mi = 0; mi < 4; mi++)
        af[mi] = *(const bf16x8*)(&As[(wr * 64 + mi * 16 + lr) * LDK + kk * 32 + lg * 8]);
#pragma unroll
      for (int ni = 0; ni < 4; ni++)
        bfr[ni] = *(const bf16x8*)(&Bs[(wc * 64 + ni * 16 + lr) * LDK + kk * 32 + lg * 8]);
#pragma unroll
      for (int mi = 0; mi < 4; mi++)
#pragma unroll
        for (int ni = 0; ni < 4; ni++)
          acc[mi][ni] = __builtin_amdgcn_mfma_f32_16x16x32_bf16(
              af[mi], bfr[ni], acc[mi][ni], 0, 0, 0);
    }
    __syncthreads();
  }
#pragma unroll
  for (int mi = 0; mi < 4; mi++) {
#pragma unroll
    for (int ni = 0; ni < 4; ni++) {
      int col = n0 + wc * 64 + ni * 16 + lr;
#pragma unroll
      for (int r = 0; r < 4; r++) {
        int row = m0 + wr * 64 + mi * 16 + lg * 4 + r;
        C[(size_t)row * 1024 + col] = acc[mi][ni][r];
      }
    }
  }
}

// ---------------- RoPE on Q and K (in place); Q gets 1/sqrt(hd) folded ------
__global__ void rope_kernel(unsigned short* __restrict__ Q,
                            unsigned short* __restrict__ K,
                            const float* __restrict__ cosT,
                            const float* __restrict__ sinT) {
  const int nchunk = B_ * NH * T_ * (HD / 8);  // 1048576
  for (int idx = blockIdx.x * blockDim.x + threadIdx.x; idx < 2 * nchunk;
       idx += gridDim.x * blockDim.x) {
    int which = idx >= nchunk;
    int c = which ? idx - nchunk : idx;
    unsigned short* base = which ? K : Q;
    int ch = c & 7;
    int row = c >> 3;
    int tt = row & (T_ - 1);
    bf16x8 v = *(bf16x8*)(base + (size_t)row * HD + ch * 8);
    float scale = which ? 1.0f : 0.125f;
#pragma unroll
    for (int p = 0; p < 4; p++) {
      int fi = ch * 4 + p;
      float cc = cosT[tt * 32 + fi], ss = sinT[tt * 32 + fi];
      float x1 = b2f((unsigned short)v[2 * p]);
      float x2 = b2f((unsigned short)v[2 * p + 1]);
      v[2 * p] = (short)f2bf((x1 * cc - x2 * ss) * scale);
      v[2 * p + 1] = (short)f2bf((x2 * cc + x1 * ss) * scale);
    }
    *(bf16x8*)(base + (size_t)row * HD + ch * 8) = v;
  }
}

// ---------------- Flash attention v2 ----------------------------------------
// 4 waves/block, 32 q-rows/wave (128 q-rows/block), KV tile 64 double-buffered
// in LDS via global_load_lds (prefetch depth 1), XOR-swizzled (both sides).
// Block mapping: blk&7 -> XCD slot (8 bh per XCD => 4MB KV = L2), big qt first.
__global__ __launch_bounds__(256, 3) void attn_kernel(
    const unsigned short* __restrict__ Q, const unsigned short* __restrict__ K,
    const unsigned short* __restrict__ VT, unsigned short* __restrict__ O) {
  __shared__ __align__(16) unsigned short Ks[2][4096];  // [64 kv][64 d] linear
  __shared__ __align__(16) unsigned short Vs[2][4096];  // [64 d][64 t] linear
  __shared__ __align__(16) unsigned short Pl[4][32 * 72];

  const int blk = blockIdx.x;
  const int j2 = blk >> 3;
  const int bh = (blk & 7) * 8 + (j2 & 7);
  const int qt = 15 - (j2 >> 3);
  const int b = bh >> 4, h = bh & 15;
  const int tid = threadIdx.x;
  const int w = tid >> 6, l = tid & 63;
  const int lr = l & 15, lg = l >> 4;
  const int q0 = qt * 128 + w * 32;

  const unsigned short* Qb = Q + (size_t)bh * T_ * HD;
  const char* Kc = (const char*)(K + (size_t)bh * T_ * HD);
  const char* Vc = (const char*)(VT + (size_t)bh * HD * T_);

  // staging constants: chunks c0,c1 per thread (16B each), swizzled source
  const int c0 = (w * 2) * 64 + l;
  const int c1 = (w * 2 + 1) * 64 + l;
  const int r0 = c0 >> 3, r1 = c1 >> 3;
  const int sw0 = ((c0 & 7) * 16) ^ ((r0 & 7) << 4);
  const int sw1 = ((c1 & 7) * 16) ^ ((r1 & 7) << 4);
  const char* pK0 = Kc + r0 * 128 + sw0;
  const char* pK1 = Kc + r1 * 128 + sw1;
  const char* pV0 = Vc + (size_t)r0 * (T_ * 2) + sw0;
  const char* pV1 = Vc + (size_t)r1 * (T_ * 2) + sw1;

  // K advances 64 rows * 128 B = 8192 B per tile; V advances 64 cols * 2 B
  // = 128 B per (4096 B-stride) row per tile.
#define STAGE(buf, tile)                                                    \
  do {                                                                      \
    size_t kb = (size_t)(tile) * 8192;                                      \
    size_t vb = (size_t)(tile) * 128;                                       \
    gll16(pK0 + kb, (char*)Ks[buf] + (w * 2) * 1024);                       \
    gll16(pK1 + kb, (char*)Ks[buf] + (w * 2 + 1) * 1024);                   \
    gll16(pV0 + vb, (char*)Vs[buf] + (w * 2) * 1024);                       \
    gll16(pV1 + vb, (char*)Vs[buf] + (w * 2 + 1) * 1024);                   \
  } while (0)

  // Q fragments (scaled by 1/8 already via rope)
  bf16x8 aq[2][2];
#pragma unroll
  for (int m = 0; m < 2; m++)
#pragma unroll
    for (int kd = 0; kd < 2; kd++)
      aq[m][kd] = *(const bf16x8*)(Qb + (size_t)(q0 + m * 16 + lr) * HD +
                                   kd * 32 + lg * 8);

  f32x4 o[2][4];
#pragma unroll
  for (int m = 0; m < 2; m++)
#pragma unroll
    for (int f = 0; f < 4; f++) o[m][f] = (f32x4)0.f;
  float mrow[2][4], lrow[2][4];
#pragma unroll
  for (int m = 0; m < 2; m++)
#pragma unroll
    for (int r = 0; r < 4; r++) { mrow[m][r] = -1e30f; lrow[m][r] = 0.f; }

  const int nt = 2 * qt + 2;
  const int jmax = q0 >> 6;
  const int cswz = (lr & 7) << 4;

  // prologue: tile0 -> buf0 (wait), tile1 -> buf1 (in flight)
  STAGE(0, 0);
  WAITV0();
  BARRIER();
  if (nt > 1) STAGE(1, 1);

  for (int j = 0; j < nt; j++) {
    const int cur = j & 1;
    if (j <= jmax) {
      const int t0 = j * 64;
      f32x4 s[2][4];
#pragma unroll
      for (int m = 0; m < 2; m++)
#pragma unroll
        for (int sf = 0; sf < 4; sf++) s[m][sf] = (f32x4)0.f;
#pragma unroll
      for (int kd = 0; kd < 2; kd++) {
#pragma unroll
        for (int sf = 0; sf < 4; sf++) {
          int row = sf * 16 + lr;
          int off = row * 128 + ((kd * 64 + lg * 16) ^ cswz);
          bf16x8 bk = *(const bf16x8*)((const char*)Ks[cur] + off);
#pragma unroll
          for (int m = 0; m < 2; m++)
            s[m][sf] = __builtin_amdgcn_mfma_f32_16x16x32_bf16(
                aq[m][kd], bk, s[m][sf], 0, 0, 0);
        }
      }
      if (j == jmax) {
#pragma unroll
        for (int m = 0; m < 2; m++)
#pragma unroll
          for (int sf = 0; sf < 4; sf++) {
            int tcol = t0 + sf * 16 + lr;
#pragma unroll
            for (int r = 0; r < 4; r++) {
              int qrow = q0 + m * 16 + lg * 4 + r;
              if (tcol > qrow) s[m][sf][r] = -1e30f;
            }
          }
      }
      // online softmax
      float alpha[2][4];
#pragma unroll
      for (int m = 0; m < 2; m++)
#pragma unroll
        for (int r = 0; r < 4; r++) {
          float v = fmaxf(fmaxf(s[m][0][r], s[m][1][r]),
                          fmaxf(s[m][2][r], s[m][3][r]));
          v = fmaxf(v, __shfl_xor(v, 1, 64));
          v = fmaxf(v, __shfl_xor(v, 2, 64));
          v = fmaxf(v, __shfl_xor(v, 4, 64));
          v = fmaxf(v, __shfl_xor(v, 8, 64));
          float mnew = fmaxf(mrow[m][r], v);
          alpha[m][r] = __expf(mrow[m][r] - mnew);
          mrow[m][r] = mnew;
        }
      float rsum[2][4] = {{0.f, 0.f, 0.f, 0.f}, {0.f, 0.f, 0.f, 0.f}};
#pragma unroll
      for (int m = 0; m < 2; m++)
#pragma unroll
        for (int sf = 0; sf < 4; sf++)
#pragma unroll
          for (int r = 0; r < 4; r++) {
            float p = __expf(s[m][sf][r] - mrow[m][r]);
            s[m][sf][r] = p;
            rsum[m][r] += p;
          }
#pragma unroll
      for (int m = 0; m < 2; m++)
#pragma unroll
        for (int r = 0; r < 4; r++) {
          float rs = rsum[m][r];
          rs += __shfl_xor(rs, 1, 64);
          rs += __shfl_xor(rs, 2, 64);
          rs += __shfl_xor(rs, 4, 64);
          rs += __shfl_xor(rs, 8, 64);
          lrow[m][r] = lrow[m][r] * alpha[m][r] + rs;
        }
#pragma unroll
      for (int m = 0; m < 2; m++)
#pragma unroll
        for (int f = 0; f < 4; f++)
#pragma unroll
          for (int r = 0; r < 4; r++) o[m][f][r] *= alpha[m][r];
      // P -> per-wave LDS (padded, transpose to A-operand layout)
#pragma unroll
      for (int m = 0; m < 2; m++)
#pragma unroll
        for (int sf = 0; sf < 4; sf++)
#pragma unroll
          for (int r = 0; r < 4; r++)
            Pl[w][(m * 16 + lg * 4 + r) * 72 + sf * 16 + lr] =
                f2bf(s[m][sf][r]);
      // PV
#pragma unroll
      for (int kd2 = 0; kd2 < 2; kd2++) {
        bf16x8 ap[2];
#pragma unroll
        for (int m = 0; m < 2; m++)
          ap[m] = *(const bf16x8*)(&Pl[w][(m * 16 + lr) * 72 + kd2 * 32 + lg * 8]);
#pragma unroll
        for (int f = 0; f < 4; f++) {
          int row = f * 16 + lr;
          int off = row * 128 + ((kd2 * 64 + lg * 16) ^ cswz);
          bf16x8 bv = *(const bf16x8*)((const char*)Vs[cur] + off);
#pragma unroll
          for (int m = 0; m < 2; m++)
            o[m][f] = __builtin_amdgcn_mfma_f32_16x16x32_bf16(ap[m], bv,
                                                              o[m][f], 0, 0, 0);
        }
      }
    }
    BARRIER();   // (a) everyone done reading buf[cur]
    WAITV0();    // tile j+1 loads (issued a full compute phase ago) landed
    if (j + 2 < nt) STAGE(cur, j + 2);
    BARRIER();   // (b) all waves' tile j+1 staging complete
  }

  // epilogue
#pragma unroll
  for (int m = 0; m < 2; m++)
#pragma unroll
    for (int f = 0; f < 4; f++) {
      int d = f * 16 + lr;
#pragma unroll
      for (int r = 0; r < 4; r++) {
        int qrow = q0 + m * 16 + lg * 4 + r;
        float val = o[m][f][r] / lrow[m][r];
        O[((size_t)b * T_ + qrow) * DM + h * HD + d] = f2bf(val);
      }
    }
#undef STAGE
}

extern "C" void kernel_launch(void* const* d_in, const int* in_sizes, int n_in,
                              void* d_out, int out_size, void* d_ws,
                              size_t ws_size, hipStream_t stream) {
  const float* x = (const float*)d_in[0];
  const float* cosT = (const float*)d_in[1];
  const float* sinT = (const float*)d_in[2];
  const float* w_qkv = (const float*)d_in[3];
  const float* w_proj = (const float*)d_in[4];
  float* out = (float*)d_out;

  char* ws = (char*)d_ws;
  unsigned short* x16 = (unsigned short*)(ws);                  // 16 MB
  unsigned short* wqkvT = (unsigned short*)(ws + (16 << 20));   // 6 MB
  unsigned short* wprojT = (unsigned short*)(ws + (22 << 20));  // 2 MB
  unsigned short* Qb = (unsigned short*)(ws + (24 << 20));      // 16 MB
  unsigned short* Kb = (unsigned short*)(ws + (40 << 20));      // 16 MB
  unsigned short* VTb = (unsigned short*)(ws + (56 << 20));     // 16 MB
  unsigned short* Ob = x16;  // reuse: x16 dead after gemm_qkv

  cast_f32_to_bf16<<<2048, 256, 0, stream>>>(x, x16, (B_ * T_ * DM) / 8);
  transpose_cast<<<dim3(3072 / 32, 1024 / 32), dim3(32, 8), 0, stream>>>(
      w_qkv, wqkvT, 1024, 3072);
  transpose_cast<<<dim3(1024 / 32, 1024 / 32), dim3(32, 8), 0, stream>>>(
      w_proj, wprojT, 1024, 1024);
  gemm_qkv<<<dim3(3072 / BN, (B_ * T_) / BM), 256, 0, stream>>>(x16, wqkvT, Qb,
                                                                Kb, VTb);
  rope_kernel<<<4096, 256, 0, stream>>>(Qb, Kb, cosT, sinT);
  attn_kernel<<<dim3(1024), 256, 0, stream>>>(Qb, Kb, VTb, Ob);
  gemm_proj<<<dim3(1024 / BN, (B_ * T_) / BM), 256, 0, stream>>>(Ob, wprojT, out);
}

// Round 4
// 248.726 us; speedup vs baseline: 2.4180x; 1.0330x over previous
//
#include <hip/hip_runtime.h>
#include <cstdint>
#include <cstddef>

typedef __attribute__((ext_vector_type(8))) short bf16x8;
typedef __attribute__((ext_vector_type(4))) float f32x4;

#define B_ 4
#define T_ 2048
#define DM 1024
#define NH 16
#define HD 64

static __device__ __forceinline__ unsigned short f2bf(float f) {
  union { float f; unsigned int u; } v; v.f = f;
  unsigned int r = v.u + 0x7FFFu + ((v.u >> 16) & 1u);
  return (unsigned short)(r >> 16);
}
static __device__ __forceinline__ float b2f(unsigned short u) {
  union { unsigned int u; float f; } v; v.u = ((unsigned int)u) << 16;
  return v.f;
}
static __device__ __forceinline__ float exp2_fast(float x) {
  float r;
  asm volatile("v_exp_f32 %0, %1" : "=v"(r) : "v"(x));
  return r;
}

static __device__ __forceinline__ void gll16(const void* g, void* l) {
  __builtin_amdgcn_global_load_lds(
      (const __attribute__((address_space(1))) void*)g,
      (__attribute__((address_space(3))) void*)l, 16, 0, 0);
}

#define BARRIER() do { asm volatile("" ::: "memory"); __builtin_amdgcn_s_barrier(); asm volatile("" ::: "memory"); } while (0)
#define WAITV0() asm volatile("s_waitcnt vmcnt(0)" ::: "memory")

// ---------------- cast f32 -> bf16 (vectorized) ----------------
__global__ void cast_f32_to_bf16(const float* __restrict__ in,
                                 unsigned short* __restrict__ out, int n8) {
  for (int i = blockIdx.x * blockDim.x + threadIdx.x; i < n8;
       i += gridDim.x * blockDim.x) {
    const float4* p = (const float4*)(in + (size_t)i * 8);
    float4 a = p[0], b = p[1];
    bf16x8 o;
    o[0] = f2bf(a.x); o[1] = f2bf(a.y); o[2] = f2bf(a.z); o[3] = f2bf(a.w);
    o[4] = f2bf(b.x); o[5] = f2bf(b.y); o[6] = f2bf(b.z); o[7] = f2bf(b.w);
    *(bf16x8*)(out + (size_t)i * 8) = o;
  }
}

// ---------------- transpose + cast: in f32 [R][C] -> out bf16 [C][R] --------
__global__ void transpose_cast(const float* __restrict__ in,
                               unsigned short* __restrict__ out, int R, int C) {
  __shared__ unsigned short tile[32][33];
  int c0 = blockIdx.x * 32, r0 = blockIdx.y * 32;
  int tx = threadIdx.x, ty = threadIdx.y;
#pragma unroll
  for (int j = 0; j < 32; j += 8) {
    float v = in[(size_t)(r0 + ty + j) * C + c0 + tx];
    tile[tx][ty + j] = f2bf(v);
  }
  __syncthreads();
#pragma unroll
  for (int j = 0; j < 32; j += 8) {
    out[(size_t)(c0 + ty + j) * R + r0 + tx] = tile[ty + j][tx];
  }
}

// ---------------- GEMM core (m97 structure) ---------------------------------
// A [M][1024] bf16, Bt [N][1024] bf16. 128x128 tile, BK=64, 4 waves (2x2).
// Staging: global_load_lds 16B, pre-swizzled source, linear LDS dest.
// Read: ds_read_b128 with matching XOR swizzle -> uniform 8 dwords/bank.
#define GEMM_MAIN(As, Bs, Agl, Bgl, acc)                                     \
  {                                                                          \
    const char* gA = (const char*)(Agl) +                                    \
                     (size_t)(m0 + (tid >> 3)) * 2048 +                      \
                     (((tid & 7) ^ ((tid >> 3) & 7)) << 4);                  \
    const char* gB = (const char*)(Bgl) +                                    \
                     (size_t)(n0 + (tid >> 3)) * 2048 +                      \
                     (((tid & 7) ^ ((tid >> 3) & 7)) << 4);                  \
    for (int k0 = 0; k0 < 2048; k0 += 128) {                                 \
      _Pragma("unroll") for (int i = 0; i < 4; i++) {                        \
        gll16(gA + (size_t)i * 65536 + k0, (char*)(As) + i * 4096 + w * 1024);\
        gll16(gB + (size_t)i * 65536 + k0, (char*)(Bs) + i * 4096 + w * 1024);\
      }                                                                      \
      WAITV0();                                                              \
      BARRIER();                                                             \
      _Pragma("unroll") for (int kk = 0; kk < 2; kk++) {                     \
        bf16x8 af[4], bfr[4];                                                \
        const int ko = (kk * 64 + lg * 16) ^ ((lr & 7) << 4);                \
        _Pragma("unroll") for (int mi = 0; mi < 4; mi++)                     \
            af[mi] = *(const bf16x8*)((const char*)(As) +                    \
                                      (wr * 64 + mi * 16 + lr) * 128 + ko);  \
        _Pragma("unroll") for (int ni = 0; ni < 4; ni++)                     \
            bfr[ni] = *(const bf16x8*)((const char*)(Bs) +                   \
                                       (wc * 64 + ni * 16 + lr) * 128 + ko); \
        _Pragma("unroll") for (int mi = 0; mi < 4; mi++)                     \
            _Pragma("unroll") for (int ni = 0; ni < 4; ni++)                 \
                acc[mi][ni] = __builtin_amdgcn_mfma_f32_16x16x32_bf16(       \
                    af[mi], bfr[ni], acc[mi][ni], 0, 0, 0);                  \
      }                                                                      \
      BARRIER();                                                             \
    }                                                                        \
  }

// QKV GEMM: scatters output to Q [bh][t][64], K [bh][t][64], VT [bh][64][t]
__global__ __launch_bounds__(256, 3) void gemm_qkv(
    const unsigned short* __restrict__ A, const unsigned short* __restrict__ Bt,
    unsigned short* __restrict__ Qo, unsigned short* __restrict__ Ko,
    unsigned short* __restrict__ VTo) {
  __shared__ __align__(16) unsigned short As[128 * 64];
  __shared__ __align__(16) unsigned short Bs[128 * 64];
  const int m0 = blockIdx.y * 128, n0 = blockIdx.x * 128;
  const int tid = threadIdx.x;
  const int w = tid >> 6, l = tid & 63;
  const int wr = w >> 1, wc = w & 1;
  const int lr = l & 15, lg = l >> 4;
  f32x4 acc[4][4];
#pragma unroll
  for (int i = 0; i < 4; i++)
#pragma unroll
    for (int j = 0; j < 4; j++) acc[i][j] = (f32x4)0.f;

  GEMM_MAIN(As, Bs, A, Bt, acc)

#pragma unroll
  for (int mi = 0; mi < 4; mi++) {
#pragma unroll
    for (int ni = 0; ni < 4; ni++) {
      int col = n0 + wc * 64 + ni * 16 + lr;
      int which = col >> 10, hd = col & 1023;
      int h = hd >> 6, d = hd & 63;
#pragma unroll
      for (int r = 0; r < 4; r++) {
        int row = m0 + wr * 64 + mi * 16 + lg * 4 + r;
        int b = row >> 11, tt = row & 2047;
        unsigned short bv = f2bf(acc[mi][ni][r]);
        size_t bh = (size_t)(b * NH + h);
        if (which == 0)
          Qo[(bh * T_ + tt) * HD + d] = bv;
        else if (which == 1)
          Ko[(bh * T_ + tt) * HD + d] = bv;
        else
          VTo[(bh * HD + d) * T_ + tt] = bv;
      }
    }
  }
}

// Proj GEMM: A [8192][1024] bf16 @ Bt [1024][1024] bf16 -> C f32 [8192][1024]
__global__ __launch_bounds__(256, 3) void gemm_proj(
    const unsigned short* __restrict__ A, const unsigned short* __restrict__ Bt,
    float* __restrict__ C) {
  __shared__ __align__(16) unsigned short As[128 * 64];
  __shared__ __align__(16) unsigned short Bs[128 * 64];
  const int m0 = blockIdx.y * 128, n0 = blockIdx.x * 128;
  const int tid = threadIdx.x;
  const int w = tid >> 6, l = tid & 63;
  const int wr = w >> 1, wc = w & 1;
  const int lr = l & 15, lg = l >> 4;
  f32x4 acc[4][4];
#pragma unroll
  for (int i = 0; i < 4; i++)
#pragma unroll
    for (int j = 0; j < 4; j++) acc[i][j] = (f32x4)0.f;

  GEMM_MAIN(As, Bs, A, Bt, acc)

#pragma unroll
  for (int mi = 0; mi < 4; mi++) {
#pragma unroll
    for (int ni = 0; ni < 4; ni++) {
      int col = n0 + wc * 64 + ni * 16 + lr;
#pragma unroll
      for (int r = 0; r < 4; r++) {
        int row = m0 + wr * 64 + mi * 16 + lg * 4 + r;
        C[(size_t)row * 1024 + col] = acc[mi][ni][r];
      }
    }
  }
}

// ---------------- RoPE on Q and K (in place) --------------------------------
// Q gets 1/sqrt(hd) * log2(e) folded (attn softmax runs in log2 domain).
__global__ void rope_kernel(unsigned short* __restrict__ Q,
                            unsigned short* __restrict__ K,
                            const float* __restrict__ cosT,
                            const float* __restrict__ sinT) {
  const int nchunk = B_ * NH * T_ * (HD / 8);  // 1048576
  for (int idx = blockIdx.x * blockDim.x + threadIdx.x; idx < 2 * nchunk;
       idx += gridDim.x * blockDim.x) {
    int which = idx >= nchunk;
    int c = which ? idx - nchunk : idx;
    unsigned short* base = which ? K : Q;
    int ch = c & 7;
    int row = c >> 3;
    int tt = row & (T_ - 1);
    bf16x8 v = *(bf16x8*)(base + (size_t)row * HD + ch * 8);
    const float4 cc4 = *(const float4*)(cosT + tt * 32 + ch * 4);
    const float4 ss4 = *(const float4*)(sinT + tt * 32 + ch * 4);
    const float* ccp = (const float*)&cc4;
    const float* ssp = (const float*)&ss4;
    float scale = which ? 1.0f : 0.18033688f;  // 0.125 * log2(e)
#pragma unroll
    for (int p = 0; p < 4; p++) {
      float cc = ccp[p], ss = ssp[p];
      float x1 = b2f((unsigned short)v[2 * p]);
      float x2 = b2f((unsigned short)v[2 * p + 1]);
      v[2 * p] = (short)f2bf((x1 * cc - x2 * ss) * scale);
      v[2 * p + 1] = (short)f2bf((x2 * cc + x1 * ss) * scale);
    }
    *(bf16x8*)(base + (size_t)row * HD + ch * 8) = v;
  }
}

// ---------------- Flash attention v3 ----------------------------------------
// 4 waves/block, 32 q-rows/wave; KV tile 64 double-buffered via global_load_lds
// (prefetch depth 1), XOR-swizzled both sides. Softmax in log2 domain (Q
// pre-scaled by log2e/8) + defer-max (THR=8): skip rescale when max growth
// small. XCD mapping: blk&7 -> XCD, 8 bh per XCD slot.
__global__ __launch_bounds__(256, 3) void attn_kernel(
    const unsigned short* __restrict__ Q, const unsigned short* __restrict__ K,
    const unsigned short* __restrict__ VT, unsigned short* __restrict__ O) {
  __shared__ __align__(16) unsigned short Ks[2][4096];  // [64 kv][64 d]
  __shared__ __align__(16) unsigned short Vs[2][4096];  // [64 d][64 t]
  __shared__ __align__(16) unsigned short Pl[4][32 * 72];

  const int blk = blockIdx.x;
  const int j2 = blk >> 3;
  const int bh = (blk & 7) * 8 + (j2 & 7);
  const int qt = 15 - (j2 >> 3);
  const int b = bh >> 4, h = bh & 15;
  const int tid = threadIdx.x;
  const int w = tid >> 6, l = tid & 63;
  const int lr = l & 15, lg = l >> 4;
  const int q0 = qt * 128 + w * 32;

  const unsigned short* Qb = Q + (size_t)bh * T_ * HD;
  const char* Kc = (const char*)(K + (size_t)bh * T_ * HD);
  const char* Vc = (const char*)(VT + (size_t)bh * HD * T_);

  const int c0 = (w * 2) * 64 + l;
  const int c1 = (w * 2 + 1) * 64 + l;
  const int r0 = c0 >> 3, r1 = c1 >> 3;
  const int sw0 = ((c0 & 7) * 16) ^ ((r0 & 7) << 4);
  const int sw1 = ((c1 & 7) * 16) ^ ((r1 & 7) << 4);
  const char* pK0 = Kc + r0 * 128 + sw0;
  const char* pK1 = Kc + r1 * 128 + sw1;
  const char* pV0 = Vc + (size_t)r0 * (T_ * 2) + sw0;
  const char* pV1 = Vc + (size_t)r1 * (T_ * 2) + sw1;

#define STAGE(buf, tile)                                                    \
  do {                                                                      \
    size_t kb = (size_t)(tile) * 8192;                                      \
    size_t vb = (size_t)(tile) * 128;                                       \
    gll16(pK0 + kb, (char*)Ks[buf] + (w * 2) * 1024);                       \
    gll16(pK1 + kb, (char*)Ks[buf] + (w * 2 + 1) * 1024);                   \
    gll16(pV0 + vb, (char*)Vs[buf] + (w * 2) * 1024);                       \
    gll16(pV1 + vb, (char*)Vs[buf] + (w * 2 + 1) * 1024);                   \
  } while (0)

  bf16x8 aq[2][2];
#pragma unroll
  for (int m = 0; m < 2; m++)
#pragma unroll
    for (int kd = 0; kd < 2; kd++)
      aq[m][kd] = *(const bf16x8*)(Qb + (size_t)(q0 + m * 16 + lr) * HD +
                                   kd * 32 + lg * 8);

  f32x4 o[2][4];
#pragma unroll
  for (int m = 0; m < 2; m++)
#pragma unroll
    for (int f = 0; f < 4; f++) o[m][f] = (f32x4)0.f;
  float mrow[2][4], lrow[2][4];
#pragma unroll
  for (int m = 0; m < 2; m++)
#pragma unroll
    for (int r = 0; r < 4; r++) { mrow[m][r] = -1e30f; lrow[m][r] = 0.f; }

  const int nt = 2 * qt + 2;
  const int jmax = q0 >> 6;
  const int cswz = (lr & 7) << 4;

  STAGE(0, 0);
  WAITV0();
  BARRIER();
  if (nt > 1) STAGE(1, 1);

  for (int j = 0; j < nt; j++) {
    const int cur = j & 1;
    if (j <= jmax) {
      const int t0 = j * 64;
      f32x4 s[2][4];
#pragma unroll
      for (int m = 0; m < 2; m++)
#pragma unroll
        for (int sf = 0; sf < 4; sf++) s[m][sf] = (f32x4)0.f;
#pragma unroll
      for (int kd = 0; kd < 2; kd++) {
#pragma unroll
        for (int sf = 0; sf < 4; sf++) {
          int row = sf * 16 + lr;
          int off = row * 128 + ((kd * 64 + lg * 16) ^ cswz);
          bf16x8 bk = *(const bf16x8*)((const char*)Ks[cur] + off);
#pragma unroll
          for (int m = 0; m < 2; m++)
            s[m][sf] = __builtin_amdgcn_mfma_f32_16x16x32_bf16(
                aq[m][kd], bk, s[m][sf], 0, 0, 0);
        }
      }
      if (j == jmax) {
#pragma unroll
        for (int m = 0; m < 2; m++)
#pragma unroll
          for (int sf = 0; sf < 4; sf++) {
            int tcol = t0 + sf * 16 + lr;
#pragma unroll
            for (int r = 0; r < 4; r++) {
              int qrow = q0 + m * 16 + lg * 4 + r;
              if (tcol > qrow) s[m][sf][r] = -1e30f;
            }
          }
      }
      // ---- online softmax, log2 domain, defer-max (THR=8) ----
      float pmax[2][4];
      float grow = -3.0e38f;
#pragma unroll
      for (int m = 0; m < 2; m++)
#pragma unroll
        for (int r = 0; r < 4; r++) {
          float v = fmaxf(fmaxf(s[m][0][r], s[m][1][r]),
                          fmaxf(s[m][2][r], s[m][3][r]));
          v = fmaxf(v, __shfl_xor(v, 1, 64));
          v = fmaxf(v, __shfl_xor(v, 2, 64));
          v = fmaxf(v, __shfl_xor(v, 4, 64));
          v = fmaxf(v, __shfl_xor(v, 8, 64));
          pmax[m][r] = v;
          grow = fmaxf(grow, v - mrow[m][r]);
        }
      const int defer = __all(grow <= 8.0f);
      float alpha[2][4];
      if (!defer) {
#pragma unroll
        for (int m = 0; m < 2; m++)
#pragma unroll
          for (int r = 0; r < 4; r++) {
            float mnew = fmaxf(mrow[m][r], pmax[m][r]);
            alpha[m][r] = exp2_fast(mrow[m][r] - mnew);
            mrow[m][r] = mnew;
          }
      }
      float rsum[2][4] = {{0.f, 0.f, 0.f, 0.f}, {0.f, 0.f, 0.f, 0.f}};
#pragma unroll
      for (int m = 0; m < 2; m++)
#pragma unroll
        for (int sf = 0; sf < 4; sf++)
#pragma unroll
          for (int r = 0; r < 4; r++) {
            float p = exp2_fast(s[m][sf][r] - mrow[m][r]);
            s[m][sf][r] = p;
            rsum[m][r] += p;
          }
#pragma unroll
      for (int m = 0; m < 2; m++)
#pragma unroll
        for (int r = 0; r < 4; r++) {
          float rs = rsum[m][r];
          rs += __shfl_xor(rs, 1, 64);
          rs += __shfl_xor(rs, 2, 64);
          rs += __shfl_xor(rs, 4, 64);
          rs += __shfl_xor(rs, 8, 64);
          rsum[m][r] = rs;
        }
      if (!defer) {
#pragma unroll
        for (int m = 0; m < 2; m++)
#pragma unroll
          for (int r = 0; r < 4; r++)
            lrow[m][r] = lrow[m][r] * alpha[m][r] + rsum[m][r];
#pragma unroll
        for (int m = 0; m < 2; m++)
#pragma unroll
          for (int f = 0; f < 4; f++)
#pragma unroll
            for (int r = 0; r < 4; r++) o[m][f][r] *= alpha[m][r];
      } else {
#pragma unroll
        for (int m = 0; m < 2; m++)
#pragma unroll
          for (int r = 0; r < 4; r++) lrow[m][r] += rsum[m][r];
      }
      // P -> per-wave LDS (transpose to A-operand layout)
#pragma unroll
      for (int m = 0; m < 2; m++)
#pragma unroll
        for (int sf = 0; sf < 4; sf++)
#pragma unroll
          for (int r = 0; r < 4; r++)
            Pl[w][(m * 16 + lg * 4 + r) * 72 + sf * 16 + lr] =
                f2bf(s[m][sf][r]);
      // PV
#pragma unroll
      for (int kd2 = 0; kd2 < 2; kd2++) {
        bf16x8 ap[2];
#pragma unroll
        for (int m = 0; m < 2; m++)
          ap[m] = *(const bf16x8*)(&Pl[w][(m * 16 + lr) * 72 + kd2 * 32 + lg * 8]);
#pragma unroll
        for (int f = 0; f < 4; f++) {
          int row = f * 16 + lr;
          int off = row * 128 + ((kd2 * 64 + lg * 16) ^ cswz);
          bf16x8 bv = *(const bf16x8*)((const char*)Vs[cur] + off);
#pragma unroll
          for (int m = 0; m < 2; m++)
            o[m][f] = __builtin_amdgcn_mfma_f32_16x16x32_bf16(ap[m], bv,
                                                              o[m][f], 0, 0, 0);
        }
      }
    }
    BARRIER();   // (a) everyone done reading buf[cur]
    WAITV0();    // tile j+1 loads (issued a full compute phase ago) landed
    if (j + 2 < nt) STAGE(cur, j + 2);
    BARRIER();   // (b) all waves' tile j+1 staging complete
  }

  // epilogue
#pragma unroll
  for (int m = 0; m < 2; m++)
#pragma unroll
    for (int f = 0; f < 4; f++) {
      int d = f * 16 + lr;
#pragma unroll
      for (int r = 0; r < 4; r++) {
        int qrow = q0 + m * 16 + lg * 4 + r;
        float val = o[m][f][r] / lrow[m][r];
        O[((size_t)b * T_ + qrow) * DM + h * HD + d] = f2bf(val);
      }
    }
#undef STAGE
}

extern "C" void kernel_launch(void* const* d_in, const int* in_sizes, int n_in,
                              void* d_out, int out_size, void* d_ws,
                              size_t ws_size, hipStream_t stream) {
  const float* x = (const float*)d_in[0];
  const float* cosT = (const float*)d_in[1];
  const float* sinT = (const float*)d_in[2];
  const float* w_qkv = (const float*)d_in[3];
  const float* w_proj = (const float*)d_in[4];
  float* out = (float*)d_out;

  char* ws = (char*)d_ws;
  unsigned short* x16 = (unsigned short*)(ws);                  // 16 MB
  unsigned short* wqkvT = (unsigned short*)(ws + (16 << 20));   // 6 MB
  unsigned short* wprojT = (unsigned short*)(ws + (22 << 20));  // 2 MB
  unsigned short* Qb = (unsigned short*)(ws + (24 << 20));      // 16 MB
  unsigned short* Kb = (unsigned short*)(ws + (40 << 20));      // 16 MB
  unsigned short* VTb = (unsigned short*)(ws + (56 << 20));     // 16 MB
  unsigned short* Ob = x16;  // reuse: x16 dead after gemm_qkv

  cast_f32_to_bf16<<<2048, 256, 0, stream>>>(x, x16, (B_ * T_ * DM) / 8);
  transpose_cast<<<dim3(3072 / 32, 1024 / 32), dim3(32, 8), 0, stream>>>(
      w_qkv, wqkvT, 1024, 3072);
  transpose_cast<<<dim3(1024 / 32, 1024 / 32), dim3(32, 8), 0, stream>>>(
      w_proj, wprojT, 1024, 1024);
  gemm_qkv<<<dim3(3072 / 128, (B_ * T_) / 128), 256, 0, stream>>>(x16, wqkvT,
                                                                  Qb, Kb, VTb);
  rope_kernel<<<4096, 256, 0, stream>>>(Qb, Kb, cosT, sinT);
  attn_kernel<<<dim3(1024), 256, 0, stream>>>(Qb, Kb, VTb, Ob);
  gemm_proj<<<dim3(1024 / 128, (B_ * T_) / 128), 256, 0, stream>>>(Ob, wprojT,
                                                                   out);
}

// Round 5
// 203.737 us; speedup vs baseline: 2.9519x; 1.2208x over previous
//
#include <hip/hip_runtime.h>
#include <cstdint>
#include <cstddef>

typedef __attribute__((ext_vector_type(8))) short bf16x8;
typedef __attribute__((ext_vector_type(4))) float f32x4;
typedef __attribute__((ext_vector_type(16))) float f32x16;
typedef __attribute__((ext_vector_type(4))) unsigned int u32x4;

#define B_ 4
#define T_ 2048
#define DM 1024
#define NH 16
#define HD 64

static __device__ __forceinline__ unsigned short f2bf(float f) {
  union { float f; unsigned int u; } v; v.f = f;
  unsigned int r = v.u + 0x7FFFu + ((v.u >> 16) & 1u);
  return (unsigned short)(r >> 16);
}
static __device__ __forceinline__ float b2f(unsigned short u) {
  union { unsigned int u; float f; } v; v.u = ((unsigned int)u) << 16;
  return v.f;
}
static __device__ __forceinline__ float exp2_fast(float x) {
  float r;
  asm volatile("v_exp_f32 %0, %1" : "=v"(r) : "v"(x));
  return r;
}
static __device__ __forceinline__ unsigned int pack_bf2(float a, float b) {
  return (unsigned int)f2bf(a) | ((unsigned int)f2bf(b) << 16);
}

static __device__ __forceinline__ void gll16(const void* g, void* l) {
  __builtin_amdgcn_global_load_lds(
      (const __attribute__((address_space(1))) void*)g,
      (__attribute__((address_space(3))) void*)l, 16, 0, 0);
}

#define BARRIER() do { asm volatile("" ::: "memory"); __builtin_amdgcn_s_barrier(); asm volatile("" ::: "memory"); } while (0)
#define WAITV0() asm volatile("s_waitcnt vmcnt(0)" ::: "memory")

// ---------------- cast f32 -> bf16 (vectorized) ----------------
__global__ void cast_f32_to_bf16(const float* __restrict__ in,
                                 unsigned short* __restrict__ out, int n8) {
  for (int i = blockIdx.x * blockDim.x + threadIdx.x; i < n8;
       i += gridDim.x * blockDim.x) {
    const float4* p = (const float4*)(in + (size_t)i * 8);
    float4 a = p[0], b = p[1];
    bf16x8 o;
    o[0] = f2bf(a.x); o[1] = f2bf(a.y); o[2] = f2bf(a.z); o[3] = f2bf(a.w);
    o[4] = f2bf(b.x); o[5] = f2bf(b.y); o[6] = f2bf(b.z); o[7] = f2bf(b.w);
    *(bf16x8*)(out + (size_t)i * 8) = o;
  }
}

// ---------------- transpose + cast: in f32 [R][C] -> out bf16 [C][R] --------
__global__ void transpose_cast(const float* __restrict__ in,
                               unsigned short* __restrict__ out, int R, int C) {
  __shared__ unsigned short tile[32][33];
  int c0 = blockIdx.x * 32, r0 = blockIdx.y * 32;
  int tx = threadIdx.x, ty = threadIdx.y;
#pragma unroll
  for (int j = 0; j < 32; j += 8) {
    float v = in[(size_t)(r0 + ty + j) * C + c0 + tx];
    tile[tx][ty + j] = f2bf(v);
  }
  __syncthreads();
#pragma unroll
  for (int j = 0; j < 32; j += 8) {
    out[(size_t)(c0 + ty + j) * R + r0 + tx] = tile[ty + j][tx];
  }
}

// ---------------- GEMM core (m97 structure) ---------------------------------
#define GEMM_MAIN(As, Bs, Agl, Bgl, acc)                                     \
  {                                                                          \
    const char* gA = (const char*)(Agl) +                                    \
                     (size_t)(m0 + (tid >> 3)) * 2048 +                      \
                     (((tid & 7) ^ ((tid >> 3) & 7)) << 4);                  \
    const char* gB = (const char*)(Bgl) +                                    \
                     (size_t)(n0 + (tid >> 3)) * 2048 +                      \
                     (((tid & 7) ^ ((tid >> 3) & 7)) << 4);                  \
    for (int k0 = 0; k0 < 2048; k0 += 128) {                                 \
      _Pragma("unroll") for (int i = 0; i < 4; i++) {                        \
        gll16(gA + (size_t)i * 65536 + k0, (char*)(As) + i * 4096 + w * 1024);\
        gll16(gB + (size_t)i * 65536 + k0, (char*)(Bs) + i * 4096 + w * 1024);\
      }                                                                      \
      WAITV0();                                                              \
      BARRIER();                                                             \
      _Pragma("unroll") for (int kk = 0; kk < 2; kk++) {                     \
        bf16x8 af[4], bfr[4];                                                \
        const int ko = (kk * 64 + lg * 16) ^ ((lr & 7) << 4);                \
        _Pragma("unroll") for (int mi = 0; mi < 4; mi++)                     \
            af[mi] = *(const bf16x8*)((const char*)(As) +                    \
                                      (wr * 64 + mi * 16 + lr) * 128 + ko);  \
        _Pragma("unroll") for (int ni = 0; ni < 4; ni++)                     \
            bfr[ni] = *(const bf16x8*)((const char*)(Bs) +                   \
                                       (wc * 64 + ni * 16 + lr) * 128 + ko); \
        _Pragma("unroll") for (int mi = 0; mi < 4; mi++)                     \
            _Pragma("unroll") for (int ni = 0; ni < 4; ni++)                 \
                acc[mi][ni] = __builtin_amdgcn_mfma_f32_16x16x32_bf16(       \
                    af[mi], bfr[ni], acc[mi][ni], 0, 0, 0);                  \
      }                                                                      \
      BARRIER();                                                             \
    }                                                                        \
  }

// QKV GEMM: scatters output to Q [bh][t][64], K [bh][t][64], VT [bh][64][t]
__global__ __launch_bounds__(256, 3) void gemm_qkv(
    const unsigned short* __restrict__ A, const unsigned short* __restrict__ Bt,
    unsigned short* __restrict__ Qo, unsigned short* __restrict__ Ko,
    unsigned short* __restrict__ VTo) {
  __shared__ __align__(16) unsigned short As[128 * 64];
  __shared__ __align__(16) unsigned short Bs[128 * 64];
  const int m0 = blockIdx.y * 128, n0 = blockIdx.x * 128;
  const int tid = threadIdx.x;
  const int w = tid >> 6, l = tid & 63;
  const int wr = w >> 1, wc = w & 1;
  const int lr = l & 15, lg = l >> 4;
  f32x4 acc[4][4];
#pragma unroll
  for (int i = 0; i < 4; i++)
#pragma unroll
    for (int j = 0; j < 4; j++) acc[i][j] = (f32x4)0.f;

  GEMM_MAIN(As, Bs, A, Bt, acc)

#pragma unroll
  for (int mi = 0; mi < 4; mi++) {
#pragma unroll
    for (int ni = 0; ni < 4; ni++) {
      int col = n0 + wc * 64 + ni * 16 + lr;
      int which = col >> 10, hd = col & 1023;
      int h = hd >> 6, d = hd & 63;
#pragma unroll
      for (int r = 0; r < 4; r++) {
        int row = m0 + wr * 64 + mi * 16 + lg * 4 + r;
        int b = row >> 11, tt = row & 2047;
        unsigned short bv = f2bf(acc[mi][ni][r]);
        size_t bh = (size_t)(b * NH + h);
        if (which == 0)
          Qo[(bh * T_ + tt) * HD + d] = bv;
        else if (which == 1)
          Ko[(bh * T_ + tt) * HD + d] = bv;
        else
          VTo[(bh * HD + d) * T_ + tt] = bv;
      }
    }
  }
}

// Proj GEMM: A [8192][1024] bf16 @ Bt [1024][1024] bf16 -> C f32 [8192][1024]
__global__ __launch_bounds__(256, 3) void gemm_proj(
    const unsigned short* __restrict__ A, const unsigned short* __restrict__ Bt,
    float* __restrict__ C) {
  __shared__ __align__(16) unsigned short As[128 * 64];
  __shared__ __align__(16) unsigned short Bs[128 * 64];
  const int m0 = blockIdx.y * 128, n0 = blockIdx.x * 128;
  const int tid = threadIdx.x;
  const int w = tid >> 6, l = tid & 63;
  const int wr = w >> 1, wc = w & 1;
  const int lr = l & 15, lg = l >> 4;
  f32x4 acc[4][4];
#pragma unroll
  for (int i = 0; i < 4; i++)
#pragma unroll
    for (int j = 0; j < 4; j++) acc[i][j] = (f32x4)0.f;

  GEMM_MAIN(As, Bs, A, Bt, acc)

#pragma unroll
  for (int mi = 0; mi < 4; mi++) {
#pragma unroll
    for (int ni = 0; ni < 4; ni++) {
      int col = n0 + wc * 64 + ni * 16 + lr;
#pragma unroll
      for (int r = 0; r < 4; r++) {
        int row = m0 + wr * 64 + mi * 16 + lg * 4 + r;
        C[(size_t)row * 1024 + col] = acc[mi][ni][r];
      }
    }
  }
}

// ---------------- RoPE on Q and K (in place) --------------------------------
// Q gets 1/sqrt(hd) * log2(e) folded (attn softmax runs in log2 domain).
__global__ void rope_kernel(unsigned short* __restrict__ Q,
                            unsigned short* __restrict__ K,
                            const float* __restrict__ cosT,
                            const float* __restrict__ sinT) {
  const int nchunk = B_ * NH * T_ * (HD / 8);  // 1048576
  for (int idx = blockIdx.x * blockDim.x + threadIdx.x; idx < 2 * nchunk;
       idx += gridDim.x * blockDim.x) {
    int which = idx >= nchunk;
    int c = which ? idx - nchunk : idx;
    unsigned short* base = which ? K : Q;
    int ch = c & 7;
    int row = c >> 3;
    int tt = row & (T_ - 1);
    bf16x8 v = *(bf16x8*)(base + (size_t)row * HD + ch * 8);
    const float4 cc4 = *(const float4*)(cosT + tt * 32 + ch * 4);
    const float4 ss4 = *(const float4*)(sinT + tt * 32 + ch * 4);
    const float* ccp = (const float*)&cc4;
    const float* ssp = (const float*)&ss4;
    float scale = which ? 1.0f : 0.18033688f;  // 0.125 * log2(e)
#pragma unroll
    for (int p = 0; p < 4; p++) {
      float cc = ccp[p], ss = ssp[p];
      float x1 = b2f((unsigned short)v[2 * p]);
      float x2 = b2f((unsigned short)v[2 * p + 1]);
      v[2 * p] = (short)f2bf((x1 * cc - x2 * ss) * scale);
      v[2 * p + 1] = (short)f2bf((x2 * cc + x1 * ss) * scale);
    }
    *(bf16x8*)(base + (size_t)row * HD + ch * 8) = v;
  }
}

// ---------------- Flash attention v4: 32x32 swapped-QK, in-register softmax -
// 4 waves/block, 32 q-rows/wave. S^T = mfma32x32(K, Q) -> lane owns q=l&31,
// 32 kv-values in regs. Softmax = in-lane reduce + one shfl_xor(32). P packed
// to bf16 in-register, cross-half shuffle builds PV B-operand (no P LDS).
// O^T = mfma32x32(V^T, P^T). KV tiles (64) double-buffered via global_load_lds.
__global__ __launch_bounds__(256, 4) void attn_kernel(
    const unsigned short* __restrict__ Q, const unsigned short* __restrict__ K,
    const unsigned short* __restrict__ VT, unsigned short* __restrict__ O) {
  __shared__ __align__(16) unsigned short Ks[2][4096];  // [64 kv][64 d]
  __shared__ __align__(16) unsigned short Vs[2][4096];  // [64 d][64 t]

  const int blk = blockIdx.x;
  const int j2 = blk >> 3;
  const int bh = (blk & 7) * 8 + (j2 & 7);
  const int qt = 15 - (j2 >> 3);
  const int b = bh >> 4, h = bh & 15;
  const int tid = threadIdx.x;
  const int w = tid >> 6, l = tid & 63;
  const int q31 = l & 31, h5 = l >> 5;
  const int q0w = qt * 128 + w * 32;
  const int q_abs = q0w + q31;

  const unsigned short* Qb = Q + (size_t)bh * T_ * HD;
  const char* Kc = (const char*)(K + (size_t)bh * T_ * HD);
  const char* Vc = (const char*)(VT + (size_t)bh * HD * T_);

  // staging: 512 16B-chunks per buffer, pre-swizzled source, linear LDS dest
  const int c0 = (w * 2) * 64 + l;
  const int c1 = (w * 2 + 1) * 64 + l;
  const int r0 = c0 >> 3, r1 = c1 >> 3;
  const int sw0 = ((c0 & 7) * 16) ^ ((r0 & 7) << 4);
  const int sw1 = ((c1 & 7) * 16) ^ ((r1 & 7) << 4);
  const char* pK0 = Kc + r0 * 128 + sw0;
  const char* pK1 = Kc + r1 * 128 + sw1;
  const char* pV0 = Vc + (size_t)r0 * (T_ * 2) + sw0;
  const char* pV1 = Vc + (size_t)r1 * (T_ * 2) + sw1;

#define STAGE(buf, tile)                                                    \
  do {                                                                      \
    size_t kb = (size_t)(tile) * 8192;                                      \
    size_t vb = (size_t)(tile) * 128;                                       \
    gll16(pK0 + kb, (char*)Ks[buf] + (w * 2) * 1024);                       \
    gll16(pK1 + kb, (char*)Ks[buf] + (w * 2 + 1) * 1024);                   \
    gll16(pV0 + vb, (char*)Vs[buf] + (w * 2) * 1024);                       \
    gll16(pV1 + vb, (char*)Vs[buf] + (w * 2 + 1) * 1024);                   \
  } while (0)

  // Q B-fragments: col=q31, k(d) = ks4*16 + h5*8 + e  (rope-scaled already)
  bf16x8 qf[4];
#pragma unroll
  for (int ks4 = 0; ks4 < 4; ks4++)
    qf[ks4] = *(const bf16x8*)(Qb + (size_t)q_abs * HD + ks4 * 16 + h5 * 8);

  f32x16 ot0 = (f32x16)0.f, ot1 = (f32x16)0.f;
  float m_reg = -1e30f, lrow = 0.f;

  const int nt = 2 * qt + 2;
  const int jmax = q0w >> 6;

  STAGE(0, 0);
  WAITV0();
  BARRIER();
  if (nt > 1) STAGE(1, 1);

  for (int j = 0; j < nt; j++) {
    const int cur = j & 1;
    if (j <= jmax) {
      // ---- QK: S^T[kv][q], two 32-kv subtiles ----
      f32x16 st[2];
      st[0] = (f32x16)0.f;
      st[1] = (f32x16)0.f;
#pragma unroll
      for (int sub = 0; sub < 2; sub++) {
        const int row = sub * 32 + q31;
        const int sw = (row & 7) << 4;
#pragma unroll
        for (int ks4 = 0; ks4 < 4; ks4++) {
          bf16x8 kf = *(const bf16x8*)((const char*)Ks[cur] + row * 128 +
                                       ((ks4 * 32 + h5 * 16) ^ sw));
          st[sub] = __builtin_amdgcn_mfma_f32_32x32x16_bf16(kf, qf[ks4],
                                                            st[sub], 0, 0, 0);
        }
      }
      if (j == jmax) {  // causal mask on diagonal tile
        const int t0 = j * 64;
#pragma unroll
        for (int sub = 0; sub < 2; sub++)
#pragma unroll
          for (int r = 0; r < 16; r++) {
            int kv_abs = t0 + sub * 32 + (r & 3) + 8 * (r >> 2) + 4 * h5;
            if (kv_abs > q_abs) st[sub][r] = -1e30f;
          }
      }
      // ---- softmax (log2 domain), in-lane + one cross-half shuffle ----
      float pmax = -1e30f;
#pragma unroll
      for (int sub = 0; sub < 2; sub++)
#pragma unroll
        for (int r = 0; r < 16; r++) pmax = fmaxf(pmax, st[sub][r]);
      pmax = fmaxf(pmax, __shfl_xor(pmax, 32, 64));
      const int defer = __all(pmax - m_reg <= 8.0f);
      if (!defer) {
        float mnew = fmaxf(m_reg, pmax);
        float alpha = exp2_fast(m_reg - mnew);
        m_reg = mnew;
        lrow *= alpha;
#pragma unroll
        for (int r = 0; r < 16; r++) {
          ot0[r] *= alpha;
          ot1[r] *= alpha;
        }
      }
      float rsum = 0.f;
#pragma unroll
      for (int sub = 0; sub < 2; sub++)
#pragma unroll
        for (int r = 0; r < 16; r++) {
          float p = exp2_fast(st[sub][r] - m_reg);
          st[sub][r] = p;
          rsum += p;
        }
      rsum += __shfl_xor(rsum, 32, 64);
      lrow += rsum;
      // ---- pack P to bf16 dwords (per 4-reg group) ----
      unsigned int pk[2][8];
#pragma unroll
      for (int sub = 0; sub < 2; sub++)
#pragma unroll
        for (int g = 0; g < 4; g++) {
          pk[sub][2 * g] = pack_bf2(st[sub][4 * g + 0], st[sub][4 * g + 1]);
          pk[sub][2 * g + 1] = pack_bf2(st[sub][4 * g + 2], st[sub][4 * g + 3]);
        }
      // ---- build PV B-operands: frag k = kv 16*ks + 8*h5 + e ----
      bf16x8 pf[4];
#pragma unroll
      for (int sub = 0; sub < 2; sub++)
#pragma unroll
        for (int s = 0; s < 2; s++) {
          unsigned int a0 = pk[sub][4 * s + 0], a1 = pk[sub][4 * s + 1];
          unsigned int b0 = pk[sub][4 * s + 2], b1 = pk[sub][4 * s + 3];
          unsigned int send0 = h5 ? a0 : b0, send1 = h5 ? a1 : b1;
          unsigned int sh0 = (unsigned int)__shfl_xor((int)send0, 32, 64);
          unsigned int sh1 = (unsigned int)__shfl_xor((int)send1, 32, 64);
          unsigned int ow0 = h5 ? b0 : a0, ow1 = h5 ? b1 : a1;
          u32x4 fu;
          fu[0] = h5 ? sh0 : ow0;
          fu[1] = h5 ? sh1 : ow1;
          fu[2] = h5 ? ow0 : sh0;
          fu[3] = h5 ? ow1 : sh1;
          pf[sub * 2 + s] = *(bf16x8*)&fu;
        }
      // ---- PV: O^T[d][q] += V^T-frag x P^T-frag ----
#pragma unroll
      for (int ks = 0; ks < 4; ks++) {
        const int colb = ks * 32 + h5 * 16;
        {
          const int row = q31;
          bf16x8 vf = *(const bf16x8*)((const char*)Vs[cur] + row * 128 +
                                       (colb ^ ((row & 7) << 4)));
          ot0 = __builtin_amdgcn_mfma_f32_32x32x16_bf16(vf, pf[ks], ot0, 0, 0, 0);
        }
        {
          const int row = 32 + q31;
          bf16x8 vf = *(const bf16x8*)((const char*)Vs[cur] + row * 128 +
                                       (colb ^ ((row & 7) << 4)));
          ot1 = __builtin_amdgcn_mfma_f32_32x32x16_bf16(vf, pf[ks], ot1, 0, 0, 0);
        }
      }
    }
    BARRIER();   // everyone done reading buf[cur]
    WAITV0();    // tile j+1 loads (issued a full compute phase ago) landed
    if (j + 2 < nt) STAGE(cur, j + 2);
    BARRIER();   // tile j+1 staging complete
  }

  // ---- epilogue: lane owns q-row q_abs; d = dsub*32 + 8*rg + 4*h5 + j ----
  const float rcpl = 1.0f / lrow;
  unsigned short* Orow = O + ((size_t)b * T_ + q_abs) * DM + h * HD;
#pragma unroll
  for (int rg = 0; rg < 4; rg++) {
    ushort4 sv;
    sv.x = f2bf(ot0[4 * rg + 0] * rcpl);
    sv.y = f2bf(ot0[4 * rg + 1] * rcpl);
    sv.z = f2bf(ot0[4 * rg + 2] * rcpl);
    sv.w = f2bf(ot0[4 * rg + 3] * rcpl);
    *(ushort4*)(Orow + 8 * rg + 4 * h5) = sv;
    ushort4 sw_;
    sw_.x = f2bf(ot1[4 * rg + 0] * rcpl);
    sw_.y = f2bf(ot1[4 * rg + 1] * rcpl);
    sw_.z = f2bf(ot1[4 * rg + 2] * rcpl);
    sw_.w = f2bf(ot1[4 * rg + 3] * rcpl);
    *(ushort4*)(Orow + 32 + 8 * rg + 4 * h5) = sw_;
  }
#undef STAGE
}

extern "C" void kernel_launch(void* const* d_in, const int* in_sizes, int n_in,
                              void* d_out, int out_size, void* d_ws,
                              size_t ws_size, hipStream_t stream) {
  const float* x = (const float*)d_in[0];
  const float* cosT = (const float*)d_in[1];
  const float* sinT = (const float*)d_in[2];
  const float* w_qkv = (const float*)d_in[3];
  const float* w_proj = (const float*)d_in[4];
  float* out = (float*)d_out;

  char* ws = (char*)d_ws;
  unsigned short* x16 = (unsigned short*)(ws);                  // 16 MB
  unsigned short* wqkvT = (unsigned short*)(ws + (16 << 20));   // 6 MB
  unsigned short* wprojT = (unsigned short*)(ws + (22 << 20));  // 2 MB
  unsigned short* Qb = (unsigned short*)(ws + (24 << 20));      // 16 MB
  unsigned short* Kb = (unsigned short*)(ws + (40 << 20));      // 16 MB
  unsigned short* VTb = (unsigned short*)(ws + (56 << 20));     // 16 MB
  unsigned short* Ob = x16;  // reuse: x16 dead after gemm_qkv

  cast_f32_to_bf16<<<2048, 256, 0, stream>>>(x, x16, (B_ * T_ * DM) / 8);
  transpose_cast<<<dim3(3072 / 32, 1024 / 32), dim3(32, 8), 0, stream>>>(
      w_qkv, wqkvT, 1024, 3072);
  transpose_cast<<<dim3(1024 / 32, 1024 / 32), dim3(32, 8), 0, stream>>>(
      w_proj, wprojT, 1024, 1024);
  gemm_qkv<<<dim3(3072 / 128, (B_ * T_) / 128), 256, 0, stream>>>(x16, wqkvT,
                                                                  Qb, Kb, VTb);
  rope_kernel<<<4096, 256, 0, stream>>>(Qb, Kb, cosT, sinT);
  attn_kernel<<<dim3(1024), 256, 0, stream>>>(Qb, Kb, VTb, Ob);
  gemm_proj<<<dim3(1024 / 128, (B_ * T_) / 128), 256, 0, stream>>>(Ob, wprojT,
                                                                   out);
}

// Round 6
// 202.233 us; speedup vs baseline: 2.9739x; 1.0074x over previous
//
#include <hip/hip_runtime.h>
#include <cstdint>
#include <cstddef>

typedef __attribute__((ext_vector_type(8))) short bf16x8;
typedef __attribute__((ext_vector_type(4))) float f32x4;
typedef __attribute__((ext_vector_type(16))) float f32x16;
typedef __attribute__((ext_vector_type(4))) unsigned int u32x4;

#define B_ 4
#define T_ 2048
#define DM 1024
#define NH 16
#define HD 64

static __device__ __forceinline__ unsigned short f2bf(float f) {
  union { float f; unsigned int u; } v; v.f = f;
  unsigned int r = v.u + 0x7FFFu + ((v.u >> 16) & 1u);
  return (unsigned short)(r >> 16);
}
static __device__ __forceinline__ float b2f(unsigned short u) {
  union { unsigned int u; float f; } v; v.u = ((unsigned int)u) << 16;
  return v.f;
}
static __device__ __forceinline__ float exp2_fast(float x) {
  float r;
  asm volatile("v_exp_f32 %0, %1" : "=v"(r) : "v"(x));
  return r;
}
static __device__ __forceinline__ unsigned int pack_bf2(float a, float b) {
  return (unsigned int)f2bf(a) | ((unsigned int)f2bf(b) << 16);
}

static __device__ __forceinline__ void gll16(const void* g, void* l) {
  __builtin_amdgcn_global_load_lds(
      (const __attribute__((address_space(1))) void*)g,
      (__attribute__((address_space(3))) void*)l, 16, 0, 0);
}

#define BARRIER() do { asm volatile("" ::: "memory"); __builtin_amdgcn_s_barrier(); asm volatile("" ::: "memory"); } while (0)
#define WAITV0() asm volatile("s_waitcnt vmcnt(0)" ::: "memory")

// ---------------- cast f32 -> bf16 (vectorized) ----------------
__global__ void cast_f32_to_bf16(const float* __restrict__ in,
                                 unsigned short* __restrict__ out, int n8) {
  for (int i = blockIdx.x * blockDim.x + threadIdx.x; i < n8;
       i += gridDim.x * blockDim.x) {
    const float4* p = (const float4*)(in + (size_t)i * 8);
    float4 a = p[0], b = p[1];
    bf16x8 o;
    o[0] = f2bf(a.x); o[1] = f2bf(a.y); o[2] = f2bf(a.z); o[3] = f2bf(a.w);
    o[4] = f2bf(b.x); o[5] = f2bf(b.y); o[6] = f2bf(b.z); o[7] = f2bf(b.w);
    *(bf16x8*)(out + (size_t)i * 8) = o;
  }
}

// ---------------- transpose + cast: in f32 [R][C] -> out bf16 [C][R] --------
__global__ void transpose_cast(const float* __restrict__ in,
                               unsigned short* __restrict__ out, int R, int C) {
  __shared__ unsigned short tile[32][33];
  int c0 = blockIdx.x * 32, r0 = blockIdx.y * 32;
  int tx = threadIdx.x, ty = threadIdx.y;
#pragma unroll
  for (int j = 0; j < 32; j += 8) {
    float v = in[(size_t)(r0 + ty + j) * C + c0 + tx];
    tile[tx][ty + j] = f2bf(v);
  }
  __syncthreads();
#pragma unroll
  for (int j = 0; j < 32; j += 8) {
    out[(size_t)(c0 + ty + j) * R + r0 + tx] = tile[ty + j][tx];
  }
}

// ---------------- GEMM core (m97 structure) ---------------------------------
#define GEMM_MAIN(As, Bs, Agl, Bgl, acc)                                     \
  {                                                                          \
    const char* gA = (const char*)(Agl) +                                    \
                     (size_t)(m0 + (tid >> 3)) * 2048 +                      \
                     (((tid & 7) ^ ((tid >> 3) & 7)) << 4);                  \
    const char* gB = (const char*)(Bgl) +                                    \
                     (size_t)(n0 + (tid >> 3)) * 2048 +                      \
                     (((tid & 7) ^ ((tid >> 3) & 7)) << 4);                  \
    for (int k0 = 0; k0 < 2048; k0 += 128) {                                 \
      _Pragma("unroll") for (int i = 0; i < 4; i++) {                        \
        gll16(gA + (size_t)i * 65536 + k0, (char*)(As) + i * 4096 + w * 1024);\
        gll16(gB + (size_t)i * 65536 + k0, (char*)(Bs) + i * 4096 + w * 1024);\
      }                                                                      \
      WAITV0();                                                              \
      BARRIER();                                                             \
      _Pragma("unroll") for (int kk = 0; kk < 2; kk++) {                     \
        bf16x8 af[4], bfr[4];                                                \
        const int ko = (kk * 64 + lg * 16) ^ ((lr & 7) << 4);                \
        _Pragma("unroll") for (int mi = 0; mi < 4; mi++)                     \
            af[mi] = *(const bf16x8*)((const char*)(As) +                    \
                                      (wr * 64 + mi * 16 + lr) * 128 + ko);  \
        _Pragma("unroll") for (int ni = 0; ni < 4; ni++)                     \
            bfr[ni] = *(const bf16x8*)((const char*)(Bs) +                   \
                                       (wc * 64 + ni * 16 + lr) * 128 + ko); \
        _Pragma("unroll") for (int mi = 0; mi < 4; mi++)                     \
            _Pragma("unroll") for (int ni = 0; ni < 4; ni++)                 \
                acc[mi][ni] = __builtin_amdgcn_mfma_f32_16x16x32_bf16(       \
                    af[mi], bfr[ni], acc[mi][ni], 0, 0, 0);                  \
      }                                                                      \
      BARRIER();                                                             \
    }                                                                        \
  }

// QKV GEMM: scatters output to Q [bh][t][64], K [bh][t][64], VT [bh][64][t]
// Grid: 1536 1D. XCD-chunked: xcd=bid&7 owns 8 contiguous M-panels x 24 N.
__global__ __launch_bounds__(256, 3) void gemm_qkv(
    const unsigned short* __restrict__ A, const unsigned short* __restrict__ Bt,
    unsigned short* __restrict__ Qo, unsigned short* __restrict__ Ko,
    unsigned short* __restrict__ VTo) {
  __shared__ __align__(16) unsigned short As[128 * 64];
  __shared__ __align__(16) unsigned short Bs[128 * 64];
  const int bid = blockIdx.x;
  const int xcd = bid & 7;
  const int cc = bid >> 3;  // [0,192)
  const int m0 = (xcd * 8 + cc / 24) * 128;
  const int n0 = (cc % 24) * 128;
  const int tid = threadIdx.x;
  const int w = tid >> 6, l = tid & 63;
  const int wr = w >> 1, wc = w & 1;
  const int lr = l & 15, lg = l >> 4;
  f32x4 acc[4][4];
#pragma unroll
  for (int i = 0; i < 4; i++)
#pragma unroll
    for (int j = 0; j < 4; j++) acc[i][j] = (f32x4)0.f;

  GEMM_MAIN(As, Bs, A, Bt, acc)

#pragma unroll
  for (int mi = 0; mi < 4; mi++) {
#pragma unroll
    for (int ni = 0; ni < 4; ni++) {
      int col = n0 + wc * 64 + ni * 16 + lr;
      int which = col >> 10, hd = col & 1023;
      int h = hd >> 6, d = hd & 63;
#pragma unroll
      for (int r = 0; r < 4; r++) {
        int row = m0 + wr * 64 + mi * 16 + lg * 4 + r;
        int b = row >> 11, tt = row & 2047;
        unsigned short bv = f2bf(acc[mi][ni][r]);
        size_t bh = (size_t)(b * NH + h);
        if (which == 0)
          Qo[(bh * T_ + tt) * HD + d] = bv;
        else if (which == 1)
          Ko[(bh * T_ + tt) * HD + d] = bv;
        else
          VTo[(bh * HD + d) * T_ + tt] = bv;
      }
    }
  }
}

// Proj GEMM: A [8192][1024] bf16 @ Bt [1024][1024] bf16 -> C f32 [8192][1024]
// Grid: 512 1D, XCD-chunked (8 M-panels x 8 N per XCD).
__global__ __launch_bounds__(256, 3) void gemm_proj(
    const unsigned short* __restrict__ A, const unsigned short* __restrict__ Bt,
    float* __restrict__ C) {
  __shared__ __align__(16) unsigned short As[128 * 64];
  __shared__ __align__(16) unsigned short Bs[128 * 64];
  const int bid = blockIdx.x;
  const int xcd = bid & 7;
  const int cc = bid >> 3;  // [0,64)
  const int m0 = (xcd * 8 + cc / 8) * 128;
  const int n0 = (cc % 8) * 128;
  const int tid = threadIdx.x;
  const int w = tid >> 6, l = tid & 63;
  const int wr = w >> 1, wc = w & 1;
  const int lr = l & 15, lg = l >> 4;
  f32x4 acc[4][4];
#pragma unroll
  for (int i = 0; i < 4; i++)
#pragma unroll
    for (int j = 0; j < 4; j++) acc[i][j] = (f32x4)0.f;

  GEMM_MAIN(As, Bs, A, Bt, acc)

#pragma unroll
  for (int mi = 0; mi < 4; mi++) {
#pragma unroll
    for (int ni = 0; ni < 4; ni++) {
      int col = n0 + wc * 64 + ni * 16 + lr;
#pragma unroll
      for (int r = 0; r < 4; r++) {
        int row = m0 + wr * 64 + mi * 16 + lg * 4 + r;
        C[(size_t)row * 1024 + col] = acc[mi][ni][r];
      }
    }
  }
}

// ---------------- RoPE on Q and K (in place) --------------------------------
// Q gets 1/sqrt(hd) * log2(e) folded (attn softmax runs in log2 domain).
__global__ void rope_kernel(unsigned short* __restrict__ Q,
                            unsigned short* __restrict__ K,
                            const float* __restrict__ cosT,
                            const float* __restrict__ sinT) {
  const int nchunk = B_ * NH * T_ * (HD / 8);  // 1048576
  for (int idx = blockIdx.x * blockDim.x + threadIdx.x; idx < 2 * nchunk;
       idx += gridDim.x * blockDim.x) {
    int which = idx >= nchunk;
    int c = which ? idx - nchunk : idx;
    unsigned short* base = which ? K : Q;
    int ch = c & 7;
    int row = c >> 3;
    int tt = row & (T_ - 1);
    bf16x8 v = *(bf16x8*)(base + (size_t)row * HD + ch * 8);
    const float4 cc4 = *(const float4*)(cosT + tt * 32 + ch * 4);
    const float4 ss4 = *(const float4*)(sinT + tt * 32 + ch * 4);
    const float* ccp = (const float*)&cc4;
    const float* ssp = (const float*)&ss4;
    float scale = which ? 1.0f : 0.18033688f;  // 0.125 * log2(e)
#pragma unroll
    for (int p = 0; p < 4; p++) {
      float cc = ccp[p], ss = ssp[p];
      float x1 = b2f((unsigned short)v[2 * p]);
      float x2 = b2f((unsigned short)v[2 * p + 1]);
      v[2 * p] = (short)f2bf((x1 * cc - x2 * ss) * scale);
      v[2 * p + 1] = (short)f2bf((x2 * cc + x1 * ss) * scale);
    }
    *(bf16x8*)(base + (size_t)row * HD + ch * 8) = v;
  }
}

// ---------------- Flash attention v5 ----------------------------------------
// v4 structure + deeper pipeline: K triple-buffered (issue->use = 3 phases),
// V double-buffered (2 phases), counted vmcnt(6/4/0) so prefetch stays in
// flight across barriers (T4). setprio(1) around MFMA clusters (T5).
// LDS 40KB -> 4 blocks/CU.
__global__ __launch_bounds__(256, 4) void attn_kernel(
    const unsigned short* __restrict__ Q, const unsigned short* __restrict__ K,
    const unsigned short* __restrict__ VT, unsigned short* __restrict__ O) {
  __shared__ __align__(16) unsigned short Ks[3][4096];  // [64 kv][64 d]
  __shared__ __align__(16) unsigned short Vs[2][4096];  // [64 d][64 t]

  const int blk = blockIdx.x;
  const int j2 = blk >> 3;
  const int bh = (blk & 7) * 8 + (j2 & 7);
  const int qt = 15 - (j2 >> 3);
  const int b = bh >> 4, h = bh & 15;
  const int tid = threadIdx.x;
  const int w = tid >> 6, l = tid & 63;
  const int q31 = l & 31, h5 = l >> 5;
  const int q0w = qt * 128 + w * 32;
  const int q_abs = q0w + q31;

  const unsigned short* Qb = Q + (size_t)bh * T_ * HD;
  const char* Kc = (const char*)(K + (size_t)bh * T_ * HD);
  const char* Vc = (const char*)(VT + (size_t)bh * HD * T_);

  // staging: 512 16B-chunks per buffer, pre-swizzled source, linear LDS dest
  const int c0 = (w * 2) * 64 + l;
  const int c1 = (w * 2 + 1) * 64 + l;
  const int r0 = c0 >> 3, r1 = c1 >> 3;
  const int sw0 = ((c0 & 7) * 16) ^ ((r0 & 7) << 4);
  const int sw1 = ((c1 & 7) * 16) ^ ((r1 & 7) << 4);
  const char* pK0 = Kc + r0 * 128 + sw0;
  const char* pK1 = Kc + r1 * 128 + sw1;
  const char* pV0 = Vc + (size_t)r0 * (T_ * 2) + sw0;
  const char* pV1 = Vc + (size_t)r1 * (T_ * 2) + sw1;

#define SK(buf, tile)                                                       \
  do {                                                                      \
    size_t kb = (size_t)(tile) * 8192;                                      \
    gll16(pK0 + kb, (char*)Ks[buf] + (w * 2) * 1024);                       \
    gll16(pK1 + kb, (char*)Ks[buf] + (w * 2 + 1) * 1024);                   \
  } while (0)
#define SV(buf, tile)                                                       \
  do {                                                                      \
    size_t vb = (size_t)(tile) * 128;                                       \
    gll16(pV0 + vb, (char*)Vs[buf] + (w * 2) * 1024);                       \
    gll16(pV1 + vb, (char*)Vs[buf] + (w * 2 + 1) * 1024);                   \
  } while (0)

  // Q B-fragments: col=q31, k(d) = ks4*16 + h5*8 + e  (rope-scaled already)
  bf16x8 qf[4];
#pragma unroll
  for (int ks4 = 0; ks4 < 4; ks4++)
    qf[ks4] = *(const bf16x8*)(Qb + (size_t)q_abs * HD + ks4 * 16 + h5 * 8);

  f32x16 ot0 = (f32x16)0.f, ot1 = (f32x16)0.f;
  float m_reg = -1e30f, lrow = 0.f;

  const int nt = 2 * qt + 2;
  const int jmax = q0w >> 6;

  // prologue: chronological issue order K0,V0,V1,K1,K2
  SK(0, 0);
  SV(0, 0);
  if (nt > 1) {
    SV(1, 1);
    SK(1, 1);
  }
  if (nt > 2) SK(2, 2);

  int kcur = 0;
  for (int j = 0; j < nt; j++) {
    const int vcur = j & 1;
    // drain exactly through tile j's K and V; keep later stages in flight
    if (j <= nt - 3) {
      asm volatile("s_waitcnt vmcnt(6)" ::: "memory");
    } else if (j == nt - 2) {
      asm volatile("s_waitcnt vmcnt(4)" ::: "memory");
    } else {
      asm volatile("s_waitcnt vmcnt(0)" ::: "memory");
    }
    BARRIER();
    if (j <= jmax) {
      // ---- QK: S^T[kv][q], two 32-kv subtiles ----
      f32x16 st[2];
      st[0] = (f32x16)0.f;
      st[1] = (f32x16)0.f;
      __builtin_amdgcn_s_setprio(1);
#pragma unroll
      for (int sub = 0; sub < 2; sub++) {
        const int row = sub * 32 + q31;
        const int sw = (row & 7) << 4;
#pragma unroll
        for (int ks4 = 0; ks4 < 4; ks4++) {
          bf16x8 kf = *(const bf16x8*)((const char*)Ks[kcur] + row * 128 +
                                       ((ks4 * 32 + h5 * 16) ^ sw));
          st[sub] = __builtin_amdgcn_mfma_f32_32x32x16_bf16(kf, qf[ks4],
                                                            st[sub], 0, 0, 0);
        }
      }
      __builtin_amdgcn_s_setprio(0);
      if (j == jmax) {  // causal mask on diagonal tile
        const int t0 = j * 64;
#pragma unroll
        for (int sub = 0; sub < 2; sub++)
#pragma unroll
          for (int r = 0; r < 16; r++) {
            int kv_abs = t0 + sub * 32 + (r & 3) + 8 * (r >> 2) + 4 * h5;
            if (kv_abs > q_abs) st[sub][r] = -1e30f;
          }
      }
      // ---- softmax (log2 domain), in-lane + one cross-half shuffle ----
      float pmax = -1e30f;
#pragma unroll
      for (int sub = 0; sub < 2; sub++)
#pragma unroll
        for (int r = 0; r < 16; r++) pmax = fmaxf(pmax, st[sub][r]);
      pmax = fmaxf(pmax, __shfl_xor(pmax, 32, 64));
      const int defer = __all(pmax - m_reg <= 8.0f);
      if (!defer) {
        float mnew = fmaxf(m_reg, pmax);
        float alpha = exp2_fast(m_reg - mnew);
        m_reg = mnew;
        lrow *= alpha;
#pragma unroll
        for (int r = 0; r < 16; r++) {
          ot0[r] *= alpha;
          ot1[r] *= alpha;
        }
      }
      float rsum = 0.f;
#pragma unroll
      for (int sub = 0; sub < 2; sub++)
#pragma unroll
        for (int r = 0; r < 16; r++) {
          float p = exp2_fast(st[sub][r] - m_reg);
          st[sub][r] = p;
          rsum += p;
        }
      rsum += __shfl_xor(rsum, 32, 64);
      lrow += rsum;
      // ---- pack P to bf16 dwords (per 4-reg group) ----
      unsigned int pk[2][8];
#pragma unroll
      for (int sub = 0; sub < 2; sub++)
#pragma unroll
        for (int g = 0; g < 4; g++) {
          pk[sub][2 * g] = pack_bf2(st[sub][4 * g + 0], st[sub][4 * g + 1]);
          pk[sub][2 * g + 1] = pack_bf2(st[sub][4 * g + 2], st[sub][4 * g + 3]);
        }
      // ---- build PV B-operands: frag k = kv 16*ks + 8*h5 + e ----
      bf16x8 pf[4];
#pragma unroll
      for (int sub = 0; sub < 2; sub++)
#pragma unroll
        for (int s = 0; s < 2; s++) {
          unsigned int a0 = pk[sub][4 * s + 0], a1 = pk[sub][4 * s + 1];
          unsigned int b0 = pk[sub][4 * s + 2], b1 = pk[sub][4 * s + 3];
          unsigned int send0 = h5 ? a0 : b0, send1 = h5 ? a1 : b1;
          unsigned int sh0 = (unsigned int)__shfl_xor((int)send0, 32, 64);
          unsigned int sh1 = (unsigned int)__shfl_xor((int)send1, 32, 64);
          unsigned int ow0 = h5 ? b0 : a0, ow1 = h5 ? b1 : a1;
          u32x4 fu;
          fu[0] = h5 ? sh0 : ow0;
          fu[1] = h5 ? sh1 : ow1;
          fu[2] = h5 ? ow0 : sh0;
          fu[3] = h5 ? ow1 : sh1;
          pf[sub * 2 + s] = *(bf16x8*)&fu;
        }
      // ---- PV: O^T[d][q] += V^T-frag x P^T-frag ----
      __builtin_amdgcn_s_setprio(1);
#pragma unroll
      for (int ks = 0; ks < 4; ks++) {
        const int colb = ks * 32 + h5 * 16;
        {
          const int row = q31;
          bf16x8 vf = *(const bf16x8*)((const char*)Vs[vcur] + row * 128 +
                                       (colb ^ ((row & 7) << 4)));
          ot0 = __builtin_amdgcn_mfma_f32_32x32x16_bf16(vf, pf[ks], ot0, 0, 0, 0);
        }
        {
          const int row = 32 + q31;
          bf16x8 vf = *(const bf16x8*)((const char*)Vs[vcur] + row * 128 +
                                       (colb ^ ((row & 7) << 4)));
          ot1 = __builtin_amdgcn_mfma_f32_32x32x16_bf16(vf, pf[ks], ot1, 0, 0, 0);
        }
      }
      __builtin_amdgcn_s_setprio(0);
    }
    BARRIER();  // all waves done reading Ks[kcur], Vs[vcur]
    if (j + 2 < nt) SV((j + 2) & 1, j + 2);   // V first (drain-order invariant)
    if (j + 3 < nt) SK(kcur, j + 3);          // (j+3)%3 == kcur
    kcur = (kcur == 2) ? 0 : kcur + 1;
  }

  // ---- epilogue: lane owns q-row q_abs; d = dsub*32 + 8*rg + 4*h5 + j ----
  const float rcpl = 1.0f / lrow;
  unsigned short* Orow = O + ((size_t)b * T_ + q_abs) * DM + h * HD;
#pragma unroll
  for (int rg = 0; rg < 4; rg++) {
    ushort4 sv;
    sv.x = f2bf(ot0[4 * rg + 0] * rcpl);
    sv.y = f2bf(ot0[4 * rg + 1] * rcpl);
    sv.z = f2bf(ot0[4 * rg + 2] * rcpl);
    sv.w = f2bf(ot0[4 * rg + 3] * rcpl);
    *(ushort4*)(Orow + 8 * rg + 4 * h5) = sv;
    ushort4 sw_;
    sw_.x = f2bf(ot1[4 * rg + 0] * rcpl);
    sw_.y = f2bf(ot1[4 * rg + 1] * rcpl);
    sw_.z = f2bf(ot1[4 * rg + 2] * rcpl);
    sw_.w = f2bf(ot1[4 * rg + 3] * rcpl);
    *(ushort4*)(Orow + 32 + 8 * rg + 4 * h5) = sw_;
  }
#undef SK
#undef SV
}

extern "C" void kernel_launch(void* const* d_in, const int* in_sizes, int n_in,
                              void* d_out, int out_size, void* d_ws,
                              size_t ws_size, hipStream_t stream) {
  const float* x = (const float*)d_in[0];
  const float* cosT = (const float*)d_in[1];
  const float* sinT = (const float*)d_in[2];
  const float* w_qkv = (const float*)d_in[3];
  const float* w_proj = (const float*)d_in[4];
  float* out = (float*)d_out;

  char* ws = (char*)d_ws;
  unsigned short* x16 = (unsigned short*)(ws);                  // 16 MB
  unsigned short* wqkvT = (unsigned short*)(ws + (16 << 20));   // 6 MB
  unsigned short* wprojT = (unsigned short*)(ws + (22 << 20));  // 2 MB
  unsigned short* Qb = (unsigned short*)(ws + (24 << 20));      // 16 MB
  unsigned short* Kb = (unsigned short*)(ws + (40 << 20));      // 16 MB
  unsigned short* VTb = (unsigned short*)(ws + (56 << 20));     // 16 MB
  unsigned short* Ob = x16;  // reuse: x16 dead after gemm_qkv

  cast_f32_to_bf16<<<2048, 256, 0, stream>>>(x, x16, (B_ * T_ * DM) / 8);
  transpose_cast<<<dim3(3072 / 32, 1024 / 32), dim3(32, 8), 0, stream>>>(
      w_qkv, wqkvT, 1024, 3072);
  transpose_cast<<<dim3(1024 / 32, 1024 / 32), dim3(32, 8), 0, stream>>>(
      w_proj, wprojT, 1024, 1024);
  gemm_qkv<<<1536, 256, 0, stream>>>(x16, wqkvT, Qb, Kb, VTb);
  rope_kernel<<<4096, 256, 0, stream>>>(Qb, Kb, cosT, sinT);
  attn_kernel<<<1024, 256, 0, stream>>>(Qb, Kb, VTb, Ob);
  gemm_proj<<<512, 256, 0, stream>>>(Ob, wprojT, out);
}